// Round 1
// baseline (825.592 us; speedup 1.0000x reference)
//
#include <hip/hip_runtime.h>
#include <math.h>

#define B_ 8
#define H_ 32
#define W_ 32
#define P_ 1024
#define C_ 384
#define G_ 4
#define CG_ 96
#define KK_ 9
#define OCOFF_ 72
#define EPS_ 1e-5f

// ---------------- weight transposes ----------------
// w_off (72, 384, 3, 3) -> w_off_t[(kk*384+c)*72 + oc]
__global__ void k_transpose_woff(const float* __restrict__ w, float* __restrict__ wt) {
    int i = blockIdx.x * 256 + threadIdx.x;
    if (i >= KK_ * C_ * OCOFF_) return;
    int oc = i % OCOFF_;
    int r = i / OCOFF_;
    int c = r % C_;
    int kk = r / C_;
    wt[i] = w[(oc * C_ + c) * KK_ + kk];
}
// w_dcn (384, 384, 3, 3) -> w_dcn_t[(kk*384+c)*384 + oc]
__global__ void k_transpose_wdcn(const float* __restrict__ w, float* __restrict__ wt) {
    int i = blockIdx.x * 256 + threadIdx.x;
    if (i >= KK_ * C_ * C_) return;
    int oc = i % C_;
    int r = i / C_;
    int c = r % C_;
    int kk = r / C_;
    wt[i] = w[(oc * C_ + c) * KK_ + kk];
}
// w2 (384,384) -> w2_t[c*384 + oc]
__global__ void k_transpose_w2(const float* __restrict__ w, float* __restrict__ wt) {
    int i = blockIdx.x * 256 + threadIdx.x;
    if (i >= C_ * C_) return;
    int oc = i % C_;
    int c = i / C_;
    wt[i] = w[oc * C_ + c];
}

// ---------------- stage A: offset 3x3 conv as im2col GEMM ----------------
// M = B*P = 8192 (32 px per block), N = 72, K = 9*384
__global__ __launch_bounds__(256) void k_offset_conv(
        const float* __restrict__ x, const float* __restrict__ w_off_t,
        const float* __restrict__ b_off, float* __restrict__ offs) {
    __shared__ float As[32 * 33];   // [px][c] padded
    __shared__ float Bs[32 * 72];   // [c][oc]
    int t = threadIdx.x;
    int m0 = blockIdx.x * 32;
    int tr = t >> 3;   // 0..31 pixel
    int tq = t & 7;    // oc group (9 each)
    float acc[9];
#pragma unroll
    for (int j = 0; j < 9; ++j) acc[j] = b_off[tq * 9 + j];

    for (int kk = 0; kk < KK_; ++kk) {
        int ky = kk / 3 - 1, kx = kk % 3 - 1;
        for (int c0 = 0; c0 < C_; c0 += 32) {
            __syncthreads();
            // A tile: 32 px x 32 c (zero-padded im2col)
#pragma unroll
            for (int pass = 0; pass < 4; ++pass) {
                int e = pass * 256 + t;
                int pxi = e >> 5, ci = e & 31;
                int m = m0 + pxi;
                int b = m >> 10, p = m & 1023;
                int h = p >> 5, w = p & 31;
                int hh = h + ky, ww = w + kx;
                float v = 0.f;
                if (hh >= 0 && hh < H_ && ww >= 0 && ww < W_)
                    v = x[(size_t)((b << 10) + (hh << 5) + ww) * C_ + c0 + ci];
                As[pxi * 33 + ci] = v;
            }
            // B tile: 32 c x 72 oc
#pragma unroll
            for (int pass = 0; pass < 9; ++pass) {
                int e = pass * 256 + t;
                int ci = e / 72, oci = e % 72;
                Bs[ci * 72 + oci] = w_off_t[(size_t)(kk * C_ + c0 + ci) * OCOFF_ + oci];
            }
            __syncthreads();
#pragma unroll
            for (int ci = 0; ci < 32; ++ci) {
                float a = As[tr * 33 + ci];
#pragma unroll
                for (int j = 0; j < 9; ++j)
                    acc[j] += a * Bs[ci * 72 + tq * 9 + j];
            }
        }
    }
    int m = m0 + tr;
#pragma unroll
    for (int j = 0; j < 9; ++j)
        offs[(size_t)m * OCOFF_ + tq * 9 + j] = acc[j];
}

// ---------------- stage B: deformable conv (fused sampling + GEMM + BN + SiLU) ----------------
// M = 8192 (64 px/block), N = 384 (64 oc/block), K = 9*384 (kk major, c minor)
__global__ __launch_bounds__(256) void k_dcn(
        const float* __restrict__ x, const float* __restrict__ offs,
        const float* __restrict__ w_dcn_t,
        const float* __restrict__ bn_gamma, const float* __restrict__ bn_beta,
        const float* __restrict__ bn_mean, const float* __restrict__ bn_var,
        float* __restrict__ yws) {
    __shared__ float As[16 * 65];   // [kc][px] padded
    __shared__ float Bs[16 * 64];   // [kc][oc]
    __shared__ float cw[64][4];     // bilinear weights (x validity)
    __shared__ int   ca[64][4];     // clipped corner base addresses (x element index * C)
    int t = threadIdx.x;
    int m0 = blockIdx.x * 64;
    int oc0 = blockIdx.y * 64;
    int tr = t >> 4, tc = t & 15;
    float acc[4][4] = {};

    for (int kk = 0; kk < KK_; ++kk) {
        int ky = kk / 3 - 1, kx = kk % 3 - 1;
        for (int g = 0; g < G_; ++g) {
            __syncthreads();   // previous chunk's compute (and staging) done
            if (t < 64) {
                int m = m0 + t;
                int b = m >> 10, p = m & 1023;
                int h = p >> 5, w = p & 31;
                const float* ofp = offs + (size_t)m * OCOFF_ + (g * KK_ + kk) * 2;
                float dy = ofp[0], dx = ofp[1];
                float py = dy + (float)(ky + h);
                float pxf = dx + (float)(kx + w);
                float fy = floorf(py), fx = floorf(pxf);
                int iy0 = (int)fy, ix0 = (int)fx;
                float wy1 = py - fy, wx1 = pxf - fx;
                float wy0 = 1.f - wy1, wx0 = 1.f - wx1;
                int iy1 = iy0 + 1, ix1 = ix0 + 1;
                bool vy0 = (iy0 >= 0) && (iy0 < H_);
                bool vy1 = (iy1 >= 0) && (iy1 < H_);
                bool vx0 = (ix0 >= 0) && (ix0 < W_);
                bool vx1 = (ix1 >= 0) && (ix1 < W_);
                int cy0 = min(max(iy0, 0), H_ - 1), cy1 = min(max(iy1, 0), H_ - 1);
                int cx0 = min(max(ix0, 0), W_ - 1), cx1 = min(max(ix1, 0), W_ - 1);
                int base = b << 10;
                ca[t][0] = (base + (cy0 << 5) + cx0) * C_;
                ca[t][1] = (base + (cy0 << 5) + cx1) * C_;
                ca[t][2] = (base + (cy1 << 5) + cx0) * C_;
                ca[t][3] = (base + (cy1 << 5) + cx1) * C_;
                cw[t][0] = wy0 * wx0 * ((vy0 && vx0) ? 1.f : 0.f);
                cw[t][1] = wy0 * wx1 * ((vy0 && vx1) ? 1.f : 0.f);
                cw[t][2] = wy1 * wx0 * ((vy1 && vx0) ? 1.f : 0.f);
                cw[t][3] = wy1 * wx1 * ((vy1 && vx1) ? 1.f : 0.f);
            }
            for (int cg0 = 0; cg0 < CG_; cg0 += 16) {
                __syncthreads();   // coords visible / previous compute done
                // A tile: bilinear-sample 64 px x 16 c
#pragma unroll
                for (int pass = 0; pass < 4; ++pass) {
                    int e = pass * 256 + t;
                    int kc = e & 15, pxi = e >> 4;
                    int cgl = g * CG_ + cg0 + kc;
                    float v = cw[pxi][0] * x[(size_t)ca[pxi][0] + cgl]
                            + cw[pxi][1] * x[(size_t)ca[pxi][1] + cgl]
                            + cw[pxi][2] * x[(size_t)ca[pxi][2] + cgl]
                            + cw[pxi][3] * x[(size_t)ca[pxi][3] + cgl];
                    As[kc * 65 + pxi] = v;
                }
                // B tile: 16 c x 64 oc
#pragma unroll
                for (int pass = 0; pass < 4; ++pass) {
                    int e = pass * 256 + t;
                    int oci = e & 63, kc = e >> 6;
                    Bs[kc * 64 + oci] =
                        w_dcn_t[(size_t)(kk * C_ + g * CG_ + cg0 + kc) * C_ + oc0 + oci];
                }
                __syncthreads();
#pragma unroll
                for (int kc = 0; kc < 16; ++kc) {
                    float a0 = As[kc * 65 + tr];
                    float a1 = As[kc * 65 + 16 + tr];
                    float a2 = As[kc * 65 + 32 + tr];
                    float a3 = As[kc * 65 + 48 + tr];
                    float b0 = Bs[kc * 64 + tc];
                    float b1 = Bs[kc * 64 + 16 + tc];
                    float b2v = Bs[kc * 64 + 32 + tc];
                    float b3 = Bs[kc * 64 + 48 + tc];
                    acc[0][0] += a0 * b0; acc[0][1] += a0 * b1; acc[0][2] += a0 * b2v; acc[0][3] += a0 * b3;
                    acc[1][0] += a1 * b0; acc[1][1] += a1 * b1; acc[1][2] += a1 * b2v; acc[1][3] += a1 * b3;
                    acc[2][0] += a2 * b0; acc[2][1] += a2 * b1; acc[2][2] += a2 * b2v; acc[2][3] += a2 * b3;
                    acc[3][0] += a3 * b0; acc[3][1] += a3 * b1; acc[3][2] += a3 * b2v; acc[3][3] += a3 * b3;
                }
            }
        }
    }
    // epilogue: BN (inference) + SiLU, store y (b,p,c)
#pragma unroll
    for (int ci = 0; ci < 4; ++ci) {
        int oc = oc0 + ci * 16 + tc;
        float sc = bn_gamma[oc] * rsqrtf(bn_var[oc] + EPS_);
        float sh = bn_beta[oc] - bn_mean[oc] * sc;
#pragma unroll
        for (int ri = 0; ri < 4; ++ri) {
            int m = m0 + ri * 16 + tr;
            float v = acc[ri][ci] * sc + sh;
            float s = v / (1.f + expf(-v));
            yws[(size_t)m * C_ + oc] = s;
        }
    }
}

// ---------------- stage C: 1x1 projection GEMM + bias ----------------
// M = 8192, N = 384, K = 384
__global__ __launch_bounds__(256) void k_final(
        const float* __restrict__ yws, const float* __restrict__ w2_t,
        const float* __restrict__ b2, float* __restrict__ out) {
    __shared__ float As[16 * 65];
    __shared__ float Bs[16 * 64];
    int t = threadIdx.x;
    int m0 = blockIdx.x * 64;
    int oc0 = blockIdx.y * 64;
    int tr = t >> 4, tc = t & 15;
    float acc[4][4] = {};
    for (int c0 = 0; c0 < C_; c0 += 16) {
        __syncthreads();
#pragma unroll
        for (int pass = 0; pass < 4; ++pass) {
            int e = pass * 256 + t;
            int kc = e & 15, pxi = e >> 4;
            As[kc * 65 + pxi] = yws[(size_t)(m0 + pxi) * C_ + c0 + kc];
        }
#pragma unroll
        for (int pass = 0; pass < 4; ++pass) {
            int e = pass * 256 + t;
            int oci = e & 63, kc = e >> 6;
            Bs[kc * 64 + oci] = w2_t[(size_t)(c0 + kc) * C_ + oc0 + oci];
        }
        __syncthreads();
#pragma unroll
        for (int kc = 0; kc < 16; ++kc) {
            float a0 = As[kc * 65 + tr];
            float a1 = As[kc * 65 + 16 + tr];
            float a2 = As[kc * 65 + 32 + tr];
            float a3 = As[kc * 65 + 48 + tr];
            float b0 = Bs[kc * 64 + tc];
            float b1 = Bs[kc * 64 + 16 + tc];
            float b2v = Bs[kc * 64 + 32 + tc];
            float b3 = Bs[kc * 64 + 48 + tc];
            acc[0][0] += a0 * b0; acc[0][1] += a0 * b1; acc[0][2] += a0 * b2v; acc[0][3] += a0 * b3;
            acc[1][0] += a1 * b0; acc[1][1] += a1 * b1; acc[1][2] += a1 * b2v; acc[1][3] += a1 * b3;
            acc[2][0] += a2 * b0; acc[2][1] += a2 * b1; acc[2][2] += a2 * b2v; acc[2][3] += a2 * b3;
            acc[3][0] += a3 * b0; acc[3][1] += a3 * b1; acc[3][2] += a3 * b2v; acc[3][3] += a3 * b3;
        }
    }
#pragma unroll
    for (int ci = 0; ci < 4; ++ci) {
        int oc = oc0 + ci * 16 + tc;
        float bias = b2[oc];
#pragma unroll
        for (int ri = 0; ri < 4; ++ri) {
            int m = m0 + ri * 16 + tr;
            out[(size_t)m * C_ + oc] = acc[ri][ci] + bias;
        }
    }
}

extern "C" void kernel_launch(void* const* d_in, const int* in_sizes, int n_in,
                              void* d_out, int out_size, void* d_ws, size_t ws_size,
                              hipStream_t stream) {
    const float* x        = (const float*)d_in[0];
    const float* w_off    = (const float*)d_in[1];
    const float* b_off    = (const float*)d_in[2];
    const float* w_dcn    = (const float*)d_in[3];
    const float* bn_gamma = (const float*)d_in[4];
    const float* bn_beta  = (const float*)d_in[5];
    const float* bn_mean  = (const float*)d_in[6];
    const float* bn_var   = (const float*)d_in[7];
    const float* w2       = (const float*)d_in[8];
    const float* b2       = (const float*)d_in[9];

    float* ws = (float*)d_ws;
    float* w_off_t = ws;                            // 9*384*72   = 248832
    float* w_dcn_t = w_off_t + 248832;              // 9*384*384  = 1327104
    float* w2_t    = w_dcn_t + 1327104;             // 384*384    = 147456
    float* offs    = w2_t + 147456;                 // 8192*72    = 589824
    float* yws     = offs + 589824;                 // 8192*384   = 3145728
    // total ~21.8 MB of workspace

    k_transpose_woff<<<dim3((248832 + 255) / 256), dim3(256), 0, stream>>>(w_off, w_off_t);
    k_transpose_wdcn<<<dim3((1327104 + 255) / 256), dim3(256), 0, stream>>>(w_dcn, w_dcn_t);
    k_transpose_w2<<<dim3((147456 + 255) / 256), dim3(256), 0, stream>>>(w2, w2_t);

    k_offset_conv<<<dim3(256), dim3(256), 0, stream>>>(x, w_off_t, b_off, offs);

    k_dcn<<<dim3(128, 6), dim3(256), 0, stream>>>(x, offs, w_dcn_t,
                                                  bn_gamma, bn_beta, bn_mean, bn_var, yws);

    k_final<<<dim3(128, 6), dim3(256), 0, stream>>>(yws, w2_t, b2, (float*)d_out);
}

// Round 2
// 193.616 us; speedup vs baseline: 4.2641x; 4.2641x over previous
//
#include <hip/hip_runtime.h>
#include <math.h>

typedef _Float16 f16;
typedef _Float16 f16x2 __attribute__((ext_vector_type(2)));
typedef _Float16 f16x8 __attribute__((ext_vector_type(8)));
typedef float f32x4 __attribute__((ext_vector_type(4)));

#define C_ 384
#define EPS_ 1e-5f

// ws element counts (halves unless noted)
#define N_XH   3145728   // x_h  [8192][384]
#define N_WDCN 1327104   // wdcn_p [54][384][64]
#define N_WOFF 331776    // woff_p [54][96][64]
#define N_W2   147456    // w2_p [6][384][64]
#define N_OFFS 589824    // offs (f32) [8192][72]

// ---------------- pack: x->f16, weights -> [ck][oc][kc] f16 ----------------
__global__ void k_pack(const float* __restrict__ x, const float* __restrict__ w_off,
                       const float* __restrict__ w_dcn, const float* __restrict__ w2,
                       f16* __restrict__ xh, f16* __restrict__ woffp,
                       f16* __restrict__ wdcnp, f16* __restrict__ w2p) {
    long i = (long)blockIdx.x * 256 + threadIdx.x;
    if (i < 1572864) {                      // x as float2 -> f16x2
        float2 v = ((const float2*)x)[i];
        f16x2 h; h.x = (f16)v.x; h.y = (f16)v.y;
        ((f16x2*)xh)[i] = h;
    } else if (i < 1572864 + 1327104) {     // w_dcn pack [ck=kk*6+cc][384][64]
        long j = i - 1572864;
        int kc = (int)(j & 63); long r = j >> 6;
        int oc = (int)(r % 384); int ck = (int)(r / 384);
        int kk = ck / 6; int c = (ck % 6) * 64 + kc;
        wdcnp[j] = (f16)w_dcn[((long)oc * 384 + c) * 9 + kk];
    } else if (i < 1572864 + 1327104 + 331776) {  // w_off pack [ck][96][64], oc>=72 -> 0
        long j = i - (1572864 + 1327104);
        int kc = (int)(j & 63); long r = j >> 6;
        int oc = (int)(r % 96); int ck = (int)(r / 96);
        int kk = ck / 6; int c = (ck % 6) * 64 + kc;
        woffp[j] = (oc < 72) ? (f16)w_off[((long)oc * 384 + c) * 9 + kk] : (f16)0.f;
    } else if (i < 1572864 + 1327104 + 331776 + 147456) { // w2 pack [cc][384][64]
        long j = i - (1572864 + 1327104 + 331776);
        int kc = (int)(j & 63); long r = j >> 6;
        int oc = (int)(r % 384); int cc = (int)(r / 384);
        w2p[j] = (f16)w2[(long)oc * 384 + cc * 64 + kc];
    }
}

// ---------------- stage A: offset conv, M=8192 N=72(->96) K=3456 ----------------
// grid 128, 256 thr (4 waves). tile 64M x 96N. waves: 2m x 2n split.
__global__ __launch_bounds__(256, 2) void k_off_gemm(
        const f16* __restrict__ xh, const f16* __restrict__ wp,
        const float* __restrict__ b_off, float* __restrict__ offs) {
    __shared__ __attribute__((aligned(16))) f16 As[64 * 72];
    int t = threadIdx.x;
    int bx = blockIdx.x;
    bx = (bx & 7) * 16 + (bx >> 3);        // XCD swizzle: one batch image per XCD
    int m0 = bx * 64;
    int w = t >> 6, l = t & 63;
    int wm = (w & 1) * 32;                  // wave m-base (2 m-tiles)
    int wn = (w >> 1) * 48;                 // wave n-base (3 n-tiles)
    int lr = l & 15, lq = l >> 4;
    f32x4 acc[2][3] = {};

    for (int ck = 0; ck < 54; ++ck) {
        int kk = ck / 6, cc = ck % 6;
        int ky = kk / 3 - 1, kx = kk % 3 - 1;
        __syncthreads();
        // im2col stage: 64 px x 64 c, f16x8 copies (zero-pad borders)
#pragma unroll
        for (int pass = 0; pass < 2; ++pass) {
            int e = pass * 256 + t;
            int px = e >> 3, seg = e & 7;
            int m = m0 + px;
            int b = m >> 10, h = (m >> 5) & 31, ww = m & 31;
            int hh = h + ky, wv = ww + kx;
            f16x8 v = {};
            if (hh >= 0 && hh < 32 && wv >= 0 && wv < 32)
                v = *(const f16x8*)(xh + ((long)((b << 10) + (hh << 5) + wv) * 384 + cc * 64 + seg * 8));
            *(f16x8*)(&As[px * 72 + seg * 8]) = v;
        }
        __syncthreads();
        const f16* wbase = wp + (long)ck * 96 * 64;
#pragma unroll
        for (int s = 0; s < 2; ++s) {
            f16x8 bf[3];
#pragma unroll
            for (int n = 0; n < 3; ++n)
                bf[n] = *(const f16x8*)(wbase + (long)(wn + 16 * n + lr) * 64 + 32 * s + 8 * lq);
            f16x8 af[2];
#pragma unroll
            for (int mi = 0; mi < 2; ++mi)
                af[mi] = *(const f16x8*)(&As[(wm + 16 * mi + lr) * 72 + 32 * s + 8 * lq]);
#pragma unroll
            for (int mi = 0; mi < 2; ++mi)
#pragma unroll
                for (int n = 0; n < 3; ++n)
                    acc[mi][n] = __builtin_amdgcn_mfma_f32_16x16x32_f16(af[mi], bf[n], acc[mi][n], 0, 0, 0);
        }
    }
#pragma unroll
    for (int n = 0; n < 3; ++n) {
        int oc = wn + 16 * n + lr;
        if (oc < 72) {
            float bia = b_off[oc];
#pragma unroll
            for (int mi = 0; mi < 2; ++mi)
#pragma unroll
                for (int r = 0; r < 4; ++r) {
                    int m = m0 + wm + 16 * mi + 4 * lq + r;
                    offs[(long)m * 72 + oc] = acc[mi][n][r] + bia;
                }
        }
    }
}

// ---------------- stage B: DCN fused sample + GEMM + BN + SiLU ----------------
// grid (128,3), 256 thr. tile 64M x 128N. waves disjoint-n (32N each).
__global__ __launch_bounds__(256, 2) void k_dcn_gemm(
        const f16* __restrict__ xh, const float* __restrict__ offs,
        const f16* __restrict__ wp,
        const float* __restrict__ bng, const float* __restrict__ bnb,
        const float* __restrict__ bnm, const float* __restrict__ bnv,
        f16* __restrict__ yh) {
    __shared__ __attribute__((aligned(16))) f16 As[64 * 72];
    __shared__ int   ca[4][64][4];
    __shared__ f16x2 cw[4][64][4];
    int t = threadIdx.x;
    int bx = blockIdx.x;
    bx = (bx & 7) * 16 + (bx >> 3);        // XCD swizzle
    int m0 = bx * 64;
    int n0 = blockIdx.y * 128;
    int w = t >> 6, l = t & 63;
    int lr = l & 15, lq = l >> 4;
    int wn = n0 + 32 * w;                   // wave n-base, disjoint
    int spx = t >> 2, slot = t & 3;         // sampling map
    f32x4 acc[4][2] = {};

    for (int kk = 0; kk < 9; ++kk) {
        int ky = kk / 3 - 1, kx = kk % 3 - 1;
        __syncthreads();
        {   // coords for all 4 groups: t -> (g = t>>6, px = t&63)
            int px = t & 63, g = t >> 6;
            int m = m0 + px;
            int b = m >> 10, h = (m >> 5) & 31, wwp = m & 31;
            const float2 o = *(const float2*)(offs + (long)m * 72 + (g * 9 + kk) * 2);
            float py = o.x + (float)(h + ky);
            float pxx = o.y + (float)(wwp + kx);
            float fy = floorf(py), fx = floorf(pxx);
            int iy0 = (int)fy, ix0 = (int)fx;
            float wy1 = py - fy, wx1 = pxx - fx;
            float wy0 = 1.f - wy1, wx0 = 1.f - wx1;
            bool vy0 = (iy0 >= 0) && (iy0 < 32);
            bool vy1 = (iy0 + 1 >= 0) && (iy0 + 1 < 32);
            bool vx0 = (ix0 >= 0) && (ix0 < 32);
            bool vx1 = (ix0 + 1 >= 0) && (ix0 + 1 < 32);
            int cy0 = min(max(iy0, 0), 31), cy1 = min(max(iy0 + 1, 0), 31);
            int cx0 = min(max(ix0, 0), 31), cx1 = min(max(ix0 + 1, 0), 31);
            int base = b << 10;
            ca[g][px][0] = (base + (cy0 << 5) + cx0) * 768;   // byte offsets
            ca[g][px][1] = (base + (cy0 << 5) + cx1) * 768;
            ca[g][px][2] = (base + (cy1 << 5) + cx0) * 768;
            ca[g][px][3] = (base + (cy1 << 5) + cx1) * 768;
            float w00 = wy0 * wx0 * ((vy0 && vx0) ? 1.f : 0.f);
            float w01 = wy0 * wx1 * ((vy0 && vx1) ? 1.f : 0.f);
            float w10 = wy1 * wx0 * ((vy1 && vx0) ? 1.f : 0.f);
            float w11 = wy1 * wx1 * ((vy1 && vx1) ? 1.f : 0.f);
            f16 h0 = (f16)w00, h1 = (f16)w01, h2 = (f16)w10, h3 = (f16)w11;
            cw[g][px][0] = (f16x2){h0, h0};
            cw[g][px][1] = (f16x2){h1, h1};
            cw[g][px][2] = (f16x2){h2, h2};
            cw[g][px][3] = (f16x2){h3, h3};
        }
        for (int cc = 0; cc < 6; ++cc) {
            __syncthreads();    // coords visible / prev MFMA frag-reads done
            {   // sample 64px x 64c into As. thread: px = t>>2, c-range 16-aligned -> single g
                int cst = cc * 64 + 16 * slot;
                int g = cst / 96;
                const char* xb = (const char*)xh;
                int a0 = ca[g][spx][0], a1 = ca[g][spx][1], a2 = ca[g][spx][2], a3 = ca[g][spx][3];
                f16x2 w0 = cw[g][spx][0], w1 = cw[g][spx][1], w2v = cw[g][spx][2], w3 = cw[g][spx][3];
#pragma unroll
                for (int i = 0; i < 8; ++i) {
                    int c = cst + 2 * i;
                    f16x2 v0 = *(const f16x2*)(xb + a0 + (long)c * 2);
                    f16x2 v1 = *(const f16x2*)(xb + a1 + (long)c * 2);
                    f16x2 v2 = *(const f16x2*)(xb + a2 + (long)c * 2);
                    f16x2 v3 = *(const f16x2*)(xb + a3 + (long)c * 2);
                    f16x2 s = w0 * v0;
                    s = w1 * v1 + s;
                    s = w2v * v2 + s;
                    s = w3 * v3 + s;
                    *(f16x2*)(&As[spx * 72 + 16 * slot + 2 * i]) = s;
                }
            }
            __syncthreads();    // As visible
            const f16* wbase = wp + (long)(kk * 6 + cc) * 384 * 64;
#pragma unroll
            for (int s = 0; s < 2; ++s) {
                f16x8 bf[2];
#pragma unroll
                for (int n = 0; n < 2; ++n)
                    bf[n] = *(const f16x8*)(wbase + (long)(wn + 16 * n + lr) * 64 + 32 * s + 8 * lq);
                f16x8 af[4];
#pragma unroll
                for (int mi = 0; mi < 4; ++mi)
                    af[mi] = *(const f16x8*)(&As[(16 * mi + lr) * 72 + 32 * s + 8 * lq]);
#pragma unroll
                for (int mi = 0; mi < 4; ++mi)
#pragma unroll
                    for (int n = 0; n < 2; ++n)
                        acc[mi][n] = __builtin_amdgcn_mfma_f32_16x16x32_f16(af[mi], bf[n], acc[mi][n], 0, 0, 0);
            }
        }
    }
    // epilogue: BN + SiLU, store y f16 [m][384]
#pragma unroll
    for (int n = 0; n < 2; ++n) {
        int oc = wn + 16 * n + lr;
        float sc = bng[oc] * rsqrtf(bnv[oc] + EPS_);
        float sh = bnb[oc] - bnm[oc] * sc;
#pragma unroll
        for (int mi = 0; mi < 4; ++mi)
#pragma unroll
            for (int r = 0; r < 4; ++r) {
                int m = m0 + 16 * mi + 4 * lq + r;
                float v = acc[mi][n][r] * sc + sh;
                v = v / (1.f + __expf(-v));
                yh[(long)m * 384 + oc] = (f16)v;
            }
    }
}

// ---------------- stage C: 1x1 projection, M=8192 N=384 K=384 ----------------
// grid (128,3), 256 thr. tile 64M x 128N, waves disjoint-n.
__global__ __launch_bounds__(256, 2) void k_out_gemm(
        const f16* __restrict__ yh, const f16* __restrict__ wp,
        const float* __restrict__ b2, float* __restrict__ out) {
    __shared__ __attribute__((aligned(16))) f16 As[64 * 72];
    int t = threadIdx.x;
    int bx = blockIdx.x;
    bx = (bx & 7) * 16 + (bx >> 3);
    int m0 = bx * 64;
    int n0 = blockIdx.y * 128;
    int w = t >> 6, l = t & 63;
    int lr = l & 15, lq = l >> 4;
    int wn = n0 + 32 * w;
    f32x4 acc[4][2] = {};

    for (int cc = 0; cc < 6; ++cc) {
        __syncthreads();
#pragma unroll
        for (int pass = 0; pass < 2; ++pass) {
            int e = pass * 256 + t;
            int px = e >> 3, seg = e & 7;
            *(f16x8*)(&As[px * 72 + seg * 8]) =
                *(const f16x8*)(yh + (long)(m0 + px) * 384 + cc * 64 + seg * 8);
        }
        __syncthreads();
        const f16* wbase = wp + (long)cc * 384 * 64;
#pragma unroll
        for (int s = 0; s < 2; ++s) {
            f16x8 bf[2];
#pragma unroll
            for (int n = 0; n < 2; ++n)
                bf[n] = *(const f16x8*)(wbase + (long)(wn + 16 * n + lr) * 64 + 32 * s + 8 * lq);
            f16x8 af[4];
#pragma unroll
            for (int mi = 0; mi < 4; ++mi)
                af[mi] = *(const f16x8*)(&As[(16 * mi + lr) * 72 + 32 * s + 8 * lq]);
#pragma unroll
            for (int mi = 0; mi < 4; ++mi)
#pragma unroll
                for (int n = 0; n < 2; ++n)
                    acc[mi][n] = __builtin_amdgcn_mfma_f32_16x16x32_f16(af[mi], bf[n], acc[mi][n], 0, 0, 0);
        }
    }
#pragma unroll
    for (int n = 0; n < 2; ++n) {
        int oc = wn + 16 * n + lr;
        float bia = b2[oc];
#pragma unroll
        for (int mi = 0; mi < 4; ++mi)
#pragma unroll
            for (int r = 0; r < 4; ++r) {
                int m = m0 + 16 * mi + 4 * lq + r;
                out[(long)m * 384 + oc] = acc[mi][n][r] + bia;
            }
    }
}

extern "C" void kernel_launch(void* const* d_in, const int* in_sizes, int n_in,
                              void* d_out, int out_size, void* d_ws, size_t ws_size,
                              hipStream_t stream) {
    const float* x        = (const float*)d_in[0];
    const float* w_off    = (const float*)d_in[1];
    const float* b_off    = (const float*)d_in[2];
    const float* w_dcn    = (const float*)d_in[3];
    const float* bn_gamma = (const float*)d_in[4];
    const float* bn_beta  = (const float*)d_in[5];
    const float* bn_mean  = (const float*)d_in[6];
    const float* bn_var   = (const float*)d_in[7];
    const float* w2       = (const float*)d_in[8];
    const float* b2       = (const float*)d_in[9];

    char* ws = (char*)d_ws;
    f16*   xh    = (f16*)ws;                                  ws += (size_t)N_XH * 2;
    f16*   wdcnp = (f16*)ws;                                  ws += (size_t)N_WDCN * 2;
    f16*   woffp = (f16*)ws;                                  ws += (size_t)N_WOFF * 2;
    f16*   w2p   = (f16*)ws;                                  ws += (size_t)N_W2 * 2;
    float* offs  = (float*)ws;                                ws += (size_t)N_OFFS * 4;
    f16*   yh    = (f16*)ws;                                  // N_XH halves

    k_pack<<<13200, 256, 0, stream>>>(x, w_off, w_dcn, w2, xh, woffp, wdcnp, w2p);
    k_off_gemm<<<128, 256, 0, stream>>>(xh, woffp, b_off, offs);
    k_dcn_gemm<<<dim3(128, 3), 256, 0, stream>>>(xh, offs, wdcnp,
                                                 bn_gamma, bn_beta, bn_mean, bn_var, yh);
    k_out_gemm<<<dim3(128, 3), 256, 0, stream>>>(yh, w2p, b2, (float*)d_out);
}

// Round 3
// 193.155 us; speedup vs baseline: 4.2743x; 1.0024x over previous
//
#include <hip/hip_runtime.h>
#include <math.h>

typedef _Float16 f16;
typedef _Float16 f16x2 __attribute__((ext_vector_type(2)));
typedef _Float16 f16x4 __attribute__((ext_vector_type(4)));
typedef _Float16 f16x8 __attribute__((ext_vector_type(8)));
typedef float f32x4 __attribute__((ext_vector_type(4)));

#define EPS_ 1e-5f

// ws element counts (halves unless noted)
#define N_XH   3145728   // x_h  [8192][384]
#define N_WDCN 1327104   // wdcn_p [54][384][64]
#define N_WOFF 331776    // woff_p [54][96][64]
#define N_W2   147456    // w2_p [6][384][64]
#define N_OFFS 589824    // offs (f32) [8192][72]

static __device__ __forceinline__ f16x8 sp8(f16 h) { return (f16x8){h,h,h,h,h,h,h,h}; }

// ---------------- pack: x->f16, weights -> [ck][oc][kc] f16 ----------------
__global__ void k_pack(const float* __restrict__ x, const float* __restrict__ w_off,
                       const float* __restrict__ w_dcn, const float* __restrict__ w2,
                       f16* __restrict__ xh, f16* __restrict__ woffp,
                       f16* __restrict__ wdcnp, f16* __restrict__ w2p) {
    long i = (long)blockIdx.x * 256 + threadIdx.x;
    if (i < 1572864) {                      // x as float2 -> f16x2
        float2 v = ((const float2*)x)[i];
        f16x2 h; h.x = (f16)v.x; h.y = (f16)v.y;
        ((f16x2*)xh)[i] = h;
    } else if (i < 1572864 + 1327104) {     // w_dcn pack [ck=kk*6+cc][384][64]
        long j = i - 1572864;
        int kc = (int)(j & 63); long r = j >> 6;
        int oc = (int)(r % 384); int ck = (int)(r / 384);
        int kk = ck / 6; int c = (ck % 6) * 64 + kc;
        wdcnp[j] = (f16)w_dcn[((long)oc * 384 + c) * 9 + kk];
    } else if (i < 1572864 + 1327104 + 331776) {  // w_off pack [ck][96][64], oc>=72 -> 0
        long j = i - (1572864 + 1327104);
        int kc = (int)(j & 63); long r = j >> 6;
        int oc = (int)(r % 96); int ck = (int)(r / 96);
        int kk = ck / 6; int c = (ck % 6) * 64 + kc;
        woffp[j] = (oc < 72) ? (f16)w_off[((long)oc * 384 + c) * 9 + kk] : (f16)0.f;
    } else if (i < 1572864 + 1327104 + 331776 + 147456) { // w2 pack [cc][384][64]
        long j = i - (1572864 + 1327104 + 331776);
        int kc = (int)(j & 63); long r = j >> 6;
        int oc = (int)(r % 384); int cc = (int)(r / 384);
        w2p[j] = (f16)w2[(long)oc * 384 + cc * 64 + kc];
    }
}

// ---------------- stage A: offset conv, M=8192 N=72(->96) K=3456 ----------------
// grid 256, 256 thr (4 waves). tile 32M x 96N. waves: 2m x 2n. dbuf 1-barrier pipeline.
__global__ __launch_bounds__(256, 2) void k_off_gemm(
        const f16* __restrict__ xh, const f16* __restrict__ wp,
        const float* __restrict__ b_off, float* __restrict__ offs) {
    __shared__ __attribute__((aligned(16))) f16 As[2][32 * 72];
    int t = threadIdx.x;
    int bx = blockIdx.x;
    bx = (bx & 7) * 32 + (bx >> 3);        // XCD j <- image j
    int m0 = bx * 32;
    int w = t >> 6, l = t & 63, lr = l & 15, lq = l >> 4;
    int wm = (w & 1) * 16, wn = (w >> 1) * 48;
    int px = t >> 3, slot = t & 7;
    f32x4 acc[3] = {};
    int m = m0 + px;
    int bimg = m >> 10, h = (m >> 5) & 31, ww = m & 31;

    auto ld = [&](int kk2, int cc2) -> f16x8 {
        int ky = kk2 / 3 - 1, kx = kk2 % 3 - 1;
        int hh = h + ky, wv = ww + kx;
        f16x8 v = {};
        if (hh >= 0 && hh < 32 && wv >= 0 && wv < 32)
            v = *(const f16x8*)(xh + ((long)((bimg << 10) + (hh << 5) + wv) * 384 + cc2 * 64 + 8 * slot));
        return v;
    };
    f16x8 stg = ld(0, 0);
    *(f16x8*)(&As[0][px * 72 + 8 * slot]) = stg;
    int cur = 0, kk = 0, cc = 0;
    for (int ck = 0; ck < 54; ++ck) {
        __syncthreads();
        bool hn = ck < 53;
        int kk2 = kk + (cc == 5), cc2 = (cc == 5) ? 0 : (cc + 1);
        if (hn) stg = ld(kk2, cc2);
        const f16* wbase = wp + (long)ck * (96 * 64);
#pragma unroll
        for (int s = 0; s < 2; ++s) {
            f16x8 a = *(const f16x8*)(&As[cur][(wm + lr) * 72 + 32 * s + 8 * lq]);
#pragma unroll
            for (int n = 0; n < 3; ++n) {
                f16x8 b = *(const f16x8*)(wbase + (long)(wn + 16 * n + lr) * 64 + 32 * s + 8 * lq);
                acc[n] = __builtin_amdgcn_mfma_f32_16x16x32_f16(a, b, acc[n], 0, 0, 0);
            }
        }
        if (hn) *(f16x8*)(&As[cur ^ 1][px * 72 + 8 * slot]) = stg;
        cur ^= 1; kk = kk2; cc = cc2;
    }
#pragma unroll
    for (int n = 0; n < 3; ++n) {
        int oc = wn + 16 * n + lr;
        if (oc < 72) {
            float bia = b_off[oc];
#pragma unroll
            for (int r = 0; r < 4; ++r) {
                int mm = m0 + wm + 4 * lq + r;
                offs[(long)mm * 72 + oc] = acc[n][r] + bia;
            }
        }
    }
}

// ---------------- stage B: DCN fused sample + GEMM + BN + SiLU ----------------
// grid (128,2), 512 thr (8 waves). tile 64M x 192N. waves 2m x 4n(48 each).
// 1 barrier/chunk; loads issued early, blend+LDS-write after MFMA (T14).
__global__ __launch_bounds__(512, 2) void k_dcn_gemm(
        const f16* __restrict__ xh, const float* __restrict__ offs,
        const f16* __restrict__ wp,
        const float* __restrict__ bng, const float* __restrict__ bnb,
        const float* __restrict__ bnm, const float* __restrict__ bnv,
        f16* __restrict__ yh) {
    __shared__ __attribute__((aligned(16))) f16 As[2][64 * 72];
    __shared__ __attribute__((aligned(16))) int ca[2][4][64][4];
    __shared__ __attribute__((aligned(16))) f16x4 cwl[2][4][64];
    int t = threadIdx.x;
    int bx = blockIdx.x;
    bx = (bx & 7) * 16 + (bx >> 3);        // XCD j <- image j
    int m0 = bx * 64;
    int n0 = blockIdx.y * 192;
    int w = t >> 6, l = t & 63, lr = l & 15, lq = l >> 4;
    int wm = (w & 1) * 32, wn = (w >> 1) * 48;
    int spx = t >> 3, slot = t & 7;
    const char* xb = (const char*)xh;
    f32x4 acc[2][3] = {};

    auto coords = [&](int kkn, int bufn) {
        if (t < 256) {
            int g = t >> 6, px = t & 63;
            int m = m0 + px;
            int b = m >> 10, h = (m >> 5) & 31, wwp = m & 31;
            int ky = kkn / 3 - 1, kx = kkn % 3 - 1;
            const float2 o = *(const float2*)(offs + (long)m * 72 + (g * 9 + kkn) * 2);
            float py = o.x + (float)(h + ky);
            float pxx = o.y + (float)(wwp + kx);
            float fy = floorf(py), fx = floorf(pxx);
            int iy0 = (int)fy, ix0 = (int)fx;
            float wy1 = py - fy, wx1 = pxx - fx;
            float wy0 = 1.f - wy1, wx0 = 1.f - wx1;
            bool vy0 = iy0 >= 0 && iy0 < 32, vy1 = iy0 + 1 >= 0 && iy0 + 1 < 32;
            bool vx0 = ix0 >= 0 && ix0 < 32, vx1 = ix0 + 1 >= 0 && ix0 + 1 < 32;
            int cy0 = min(max(iy0, 0), 31), cy1 = min(max(iy0 + 1, 0), 31);
            int cx0 = min(max(ix0, 0), 31), cx1 = min(max(ix0 + 1, 0), 31);
            int base = b << 10;
            ca[bufn][g][px][0] = (base + (cy0 << 5) + cx0) * 768;
            ca[bufn][g][px][1] = (base + (cy0 << 5) + cx1) * 768;
            ca[bufn][g][px][2] = (base + (cy1 << 5) + cx0) * 768;
            ca[bufn][g][px][3] = (base + (cy1 << 5) + cx1) * 768;
            f16x4 wv;
            wv.x = (f16)(wy0 * wx0 * ((vy0 && vx0) ? 1.f : 0.f));
            wv.y = (f16)(wy0 * wx1 * ((vy0 && vx1) ? 1.f : 0.f));
            wv.z = (f16)(wy1 * wx0 * ((vy1 && vx0) ? 1.f : 0.f));
            wv.w = (f16)(wy1 * wx1 * ((vy1 && vx1) ? 1.f : 0.f));
            cwl[bufn][g][px] = wv;
        }
    };

    coords(0, 0);
    __syncthreads();
    {   // prologue: sample chunk (kk=0,cc=0) into As[0]
        int cst = 8 * slot;
        int g = cst / 96;
        int4 cv = *(const int4*)(&ca[0][g][spx][0]);
        f16x4 wv = cwl[0][g][spx];
        long cb = (long)(cst * 2);
        f16x8 v0 = *(const f16x8*)(xb + cv.x + cb);
        f16x8 v1 = *(const f16x8*)(xb + cv.y + cb);
        f16x8 v2 = *(const f16x8*)(xb + cv.z + cb);
        f16x8 v3 = *(const f16x8*)(xb + cv.w + cb);
        f16x8 sv = v0 * sp8(wv.x) + v1 * sp8(wv.y) + v2 * sp8(wv.z) + v3 * sp8(wv.w);
        *(f16x8*)(&As[0][spx * 72 + 8 * slot]) = sv;
    }
    int cur = 0, kk = 0, cc = 0;
    for (int ck = 0; ck < 54; ++ck) {
        __syncthreads();
        bool hn = ck < 53;
        int kk2 = kk + (cc == 5), cc2 = (cc == 5) ? 0 : (cc + 1);
        f16x8 v0, v1, v2, v3; f16x4 wv;
        if (hn) {   // issue next chunk's corner loads NOW (consumed after MFMA)
            int cst = cc2 * 64 + 8 * slot;
            int g = cst / 96;
            int kb = kk2 & 1;
            int4 cv = *(const int4*)(&ca[kb][g][spx][0]);
            wv = cwl[kb][g][spx];
            long cb = (long)(cst * 2);
            v0 = *(const f16x8*)(xb + cv.x + cb);
            v1 = *(const f16x8*)(xb + cv.y + cb);
            v2 = *(const f16x8*)(xb + cv.z + cb);
            v3 = *(const f16x8*)(xb + cv.w + cb);
        }
        if (cc == 4 && kk < 8) coords(kk + 1, (kk + 1) & 1);
        // MFMA on As[cur]
        const f16* wbase = wp + (long)ck * (384 * 64);
#pragma unroll
        for (int s = 0; s < 2; ++s) {
            f16x8 a0 = *(const f16x8*)(&As[cur][(wm + lr) * 72 + 32 * s + 8 * lq]);
            f16x8 a1 = *(const f16x8*)(&As[cur][(wm + 16 + lr) * 72 + 32 * s + 8 * lq]);
#pragma unroll
            for (int n = 0; n < 3; ++n) {
                f16x8 b = *(const f16x8*)(wbase + (long)(n0 + wn + 16 * n + lr) * 64 + 32 * s + 8 * lq);
                acc[0][n] = __builtin_amdgcn_mfma_f32_16x16x32_f16(a0, b, acc[0][n], 0, 0, 0);
                acc[1][n] = __builtin_amdgcn_mfma_f32_16x16x32_f16(a1, b, acc[1][n], 0, 0, 0);
            }
        }
        if (hn) {   // blend + write into the other buffer (loads have had MFMA-time)
            f16x8 sv = v0 * sp8(wv.x) + v1 * sp8(wv.y) + v2 * sp8(wv.z) + v3 * sp8(wv.w);
            *(f16x8*)(&As[cur ^ 1][spx * 72 + 8 * slot]) = sv;
        }
        cur ^= 1; kk = kk2; cc = cc2;
    }
    // epilogue: BN + SiLU, store y f16 [m][384]
#pragma unroll
    for (int n = 0; n < 3; ++n) {
        int oc = n0 + wn + 16 * n + lr;
        float sc = bng[oc] * rsqrtf(bnv[oc] + EPS_);
        float sh = bnb[oc] - bnm[oc] * sc;
#pragma unroll
        for (int mi = 0; mi < 2; ++mi)
#pragma unroll
            for (int r = 0; r < 4; ++r) {
                int m = m0 + wm + 16 * mi + 4 * lq + r;
                float v = acc[mi][n][r] * sc + sh;
                v = v / (1.f + __expf(-v));
                yh[(long)m * 384 + oc] = (f16)v;
            }
    }
}

// ---------------- stage C: 1x1 projection, M=8192 N=384 K=384 ----------------
// grid (256,3), 256 thr. tile 32M x 128N, 4 waves n-split 32. dbuf pipeline.
__global__ __launch_bounds__(256, 4) void k_out_gemm(
        const f16* __restrict__ yh, const f16* __restrict__ wp,
        const float* __restrict__ b2, float* __restrict__ out) {
    __shared__ __attribute__((aligned(16))) f16 As[2][32 * 72];
    int t = threadIdx.x;
    int bx = blockIdx.x;
    bx = (bx & 7) * 32 + (bx >> 3);
    int m0 = bx * 32, n0 = blockIdx.y * 128;
    int w = t >> 6, l = t & 63, lr = l & 15, lq = l >> 4;
    int wn = w * 32;
    int px = t >> 3, slot = t & 7;
    f32x4 acc[2][2] = {};
    const f16* arow = yh + (long)(m0 + px) * 384 + 8 * slot;
    f16x8 stg = *(const f16x8*)(arow);
    *(f16x8*)(&As[0][px * 72 + 8 * slot]) = stg;
    int cur = 0;
    for (int cc = 0; cc < 6; ++cc) {
        __syncthreads();
        bool hn = cc < 5;
        if (hn) stg = *(const f16x8*)(arow + (cc + 1) * 64);
        const f16* wbase = wp + (long)cc * (384 * 64);
#pragma unroll
        for (int s = 0; s < 2; ++s) {
            f16x8 a0 = *(const f16x8*)(&As[cur][(lr) * 72 + 32 * s + 8 * lq]);
            f16x8 a1 = *(const f16x8*)(&As[cur][(16 + lr) * 72 + 32 * s + 8 * lq]);
#pragma unroll
            for (int n = 0; n < 2; ++n) {
                f16x8 b = *(const f16x8*)(wbase + (long)(n0 + wn + 16 * n + lr) * 64 + 32 * s + 8 * lq);
                acc[0][n] = __builtin_amdgcn_mfma_f32_16x16x32_f16(a0, b, acc[0][n], 0, 0, 0);
                acc[1][n] = __builtin_amdgcn_mfma_f32_16x16x32_f16(a1, b, acc[1][n], 0, 0, 0);
            }
        }
        if (hn) *(f16x8*)(&As[cur ^ 1][px * 72 + 8 * slot]) = stg;
        cur ^= 1;
    }
#pragma unroll
    for (int n = 0; n < 2; ++n) {
        int oc = n0 + wn + 16 * n + lr;
        float bia = b2[oc];
#pragma unroll
        for (int mi = 0; mi < 2; ++mi)
#pragma unroll
            for (int r = 0; r < 4; ++r) {
                int m = m0 + 16 * mi + 4 * lq + r;
                out[(long)m * 384 + oc] = acc[mi][n][r] + bia;
            }
    }
}

extern "C" void kernel_launch(void* const* d_in, const int* in_sizes, int n_in,
                              void* d_out, int out_size, void* d_ws, size_t ws_size,
                              hipStream_t stream) {
    const float* x        = (const float*)d_in[0];
    const float* w_off    = (const float*)d_in[1];
    const float* b_off    = (const float*)d_in[2];
    const float* w_dcn    = (const float*)d_in[3];
    const float* bn_gamma = (const float*)d_in[4];
    const float* bn_beta  = (const float*)d_in[5];
    const float* bn_mean  = (const float*)d_in[6];
    const float* bn_var   = (const float*)d_in[7];
    const float* w2       = (const float*)d_in[8];
    const float* b2       = (const float*)d_in[9];

    char* ws = (char*)d_ws;
    f16*   xh    = (f16*)ws;                                  ws += (size_t)N_XH * 2;
    f16*   wdcnp = (f16*)ws;                                  ws += (size_t)N_WDCN * 2;
    f16*   woffp = (f16*)ws;                                  ws += (size_t)N_WOFF * 2;
    f16*   w2p   = (f16*)ws;                                  ws += (size_t)N_W2 * 2;
    float* offs  = (float*)ws;                                ws += (size_t)N_OFFS * 4;
    f16*   yh    = (f16*)ws;                                  // N_XH halves

    k_pack<<<13200, 256, 0, stream>>>(x, w_off, w_dcn, w2, xh, woffp, wdcnp, w2p);
    k_off_gemm<<<256, 256, 0, stream>>>(xh, woffp, b_off, offs);
    k_dcn_gemm<<<dim3(128, 2), 512, 0, stream>>>(xh, offs, wdcnp,
                                                 bn_gamma, bn_beta, bn_mean, bn_var, yh);
    k_out_gemm<<<dim3(256, 3), 256, 0, stream>>>(yh, w2p, b2, (float*)d_out);
}

// Round 4
// 152.869 us; speedup vs baseline: 5.4007x; 1.2635x over previous
//
#include <hip/hip_runtime.h>
#include <math.h>

typedef _Float16 f16;
typedef _Float16 f16x2 __attribute__((ext_vector_type(2)));
typedef _Float16 f16x4 __attribute__((ext_vector_type(4)));
typedef _Float16 f16x8 __attribute__((ext_vector_type(8)));
typedef float f32x4 __attribute__((ext_vector_type(4)));

#define EPS_ 1e-5f

// ws element counts (halves unless noted)
#define N_XH   3145728   // x_h  [8192][384]
#define N_WDCN 1327104   // wdcn_p [54][384][64]
#define N_WOFF 331776    // woff_p [54][96][64]
#define N_W2   147456    // w2_p [6][384][64]
#define N_OFFS 589824    // offs (f32) [8192][72]
#define N_AS   28311552  // A_s [8192][3456]  (big-ws path only)

#define WS_NEED ((size_t)(N_XH + N_WDCN + N_WOFF + N_W2 + N_AS + N_XH) * 2 + (size_t)N_OFFS * 4)

static __device__ __forceinline__ f16x8 sp8(f16 h) { return (f16x8){h,h,h,h,h,h,h,h}; }

#define GLD_LDS16(g, l) __builtin_amdgcn_global_load_lds( \
    (const __attribute__((address_space(1))) void*)(g),   \
    (__attribute__((address_space(3))) void*)(l), 16, 0, 0)

// ---------------- pack: x->f16, weights -> [ck][oc][kc] f16 ----------------
__global__ void k_pack(const float* __restrict__ x, const float* __restrict__ w_off,
                       const float* __restrict__ w_dcn, const float* __restrict__ w2,
                       f16* __restrict__ xh, f16* __restrict__ woffp,
                       f16* __restrict__ wdcnp, f16* __restrict__ w2p) {
    long i = (long)blockIdx.x * 256 + threadIdx.x;
    if (i < 1572864) {                      // x as float2 -> f16x2
        float2 v = ((const float2*)x)[i];
        f16x2 h; h.x = (f16)v.x; h.y = (f16)v.y;
        ((f16x2*)xh)[i] = h;
    } else if (i < 1572864 + 1327104) {     // w_dcn pack [ck=kk*6+cc][384][64]
        long j = i - 1572864;
        int kc = (int)(j & 63); long r = j >> 6;
        int oc = (int)(r % 384); int ck = (int)(r / 384);
        int kk = ck / 6; int c = (ck % 6) * 64 + kc;
        wdcnp[j] = (f16)w_dcn[((long)oc * 384 + c) * 9 + kk];
    } else if (i < 1572864 + 1327104 + 331776) {  // w_off pack [ck][96][64], oc>=72 -> 0
        long j = i - (1572864 + 1327104);
        int kc = (int)(j & 63); long r = j >> 6;
        int oc = (int)(r % 96); int ck = (int)(r / 96);
        int kk = ck / 6; int c = (ck % 6) * 64 + kc;
        woffp[j] = (oc < 72) ? (f16)w_off[((long)oc * 384 + c) * 9 + kk] : (f16)0.f;
    } else if (i < 1572864 + 1327104 + 331776 + 147456) { // w2 pack [cc][384][64]
        long j = i - (1572864 + 1327104 + 331776);
        int kc = (int)(j & 63); long r = j >> 6;
        int oc = (int)(r % 384); int cc = (int)(r / 384);
        w2p[j] = (f16)w2[(long)oc * 384 + cc * 64 + kc];
    }
}

// ---------------- stage A: offset conv, M=8192 N=72(->96) K=3456 ----------------
__global__ __launch_bounds__(256, 2) void k_off_gemm(
        const f16* __restrict__ xh, const f16* __restrict__ wp,
        const float* __restrict__ b_off, float* __restrict__ offs) {
    __shared__ __attribute__((aligned(16))) f16 As[2][32 * 72];
    int t = threadIdx.x;
    int bx = blockIdx.x;
    bx = (bx & 7) * 32 + (bx >> 3);        // XCD j <- image j
    int m0 = bx * 32;
    int w = t >> 6, l = t & 63, lr = l & 15, lq = l >> 4;
    int wm = (w & 1) * 16, wn = (w >> 1) * 48;
    int px = t >> 3, slot = t & 7;
    f32x4 acc[3] = {};
    int m = m0 + px;
    int bimg = m >> 10, h = (m >> 5) & 31, ww = m & 31;

    auto ld = [&](int kk2, int cc2) -> f16x8 {
        int ky = kk2 / 3 - 1, kx = kk2 % 3 - 1;
        int hh = h + ky, wv = ww + kx;
        f16x8 v = {};
        if (hh >= 0 && hh < 32 && wv >= 0 && wv < 32)
            v = *(const f16x8*)(xh + ((long)((bimg << 10) + (hh << 5) + wv) * 384 + cc2 * 64 + 8 * slot));
        return v;
    };
    f16x8 stg = ld(0, 0);
    *(f16x8*)(&As[0][px * 72 + 8 * slot]) = stg;
    int cur = 0, kk = 0, cc = 0;
    for (int ck = 0; ck < 54; ++ck) {
        __syncthreads();
        bool hn = ck < 53;
        int kk2 = kk + (cc == 5), cc2 = (cc == 5) ? 0 : (cc + 1);
        if (hn) stg = ld(kk2, cc2);
        const f16* wbase = wp + (long)ck * (96 * 64);
#pragma unroll
        for (int s = 0; s < 2; ++s) {
            f16x8 a = *(const f16x8*)(&As[cur][(wm + lr) * 72 + 32 * s + 8 * lq]);
#pragma unroll
            for (int n = 0; n < 3; ++n) {
                f16x8 b = *(const f16x8*)(wbase + (long)(wn + 16 * n + lr) * 64 + 32 * s + 8 * lq);
                acc[n] = __builtin_amdgcn_mfma_f32_16x16x32_f16(a, b, acc[n], 0, 0, 0);
            }
        }
        if (hn) *(f16x8*)(&As[cur ^ 1][px * 72 + 8 * slot]) = stg;
        cur ^= 1; kk = kk2; cc = cc2;
    }
#pragma unroll
    for (int n = 0; n < 3; ++n) {
        int oc = wn + 16 * n + lr;
        if (oc < 72) {
            float bia = b_off[oc];
#pragma unroll
            for (int r = 0; r < 4; ++r) {
                int mm = m0 + wm + 4 * lq + r;
                offs[(long)mm * 72 + oc] = acc[n][r] + bia;
            }
        }
    }
}

// ---------------- stage B1: sampler — materialize A_s[8192][3456] ----------------
// grid 768: bid = kkblk*256 + mgRaw. block: 32 m x 3 kk x 4 g x 2 half-groups.
__global__ __launch_bounds__(256) void k_sample(
        const f16* __restrict__ xh, const float* __restrict__ offs,
        f16* __restrict__ As_g) {
    int t = threadIdx.x;
    int bid = blockIdx.x;
    int kk0 = (bid >> 8) * 3;
    int mgRaw = bid & 255;
    int mg = (mgRaw & 7) * 32 + (mgRaw >> 3);   // XCD i <- image i
    int mbase = mg * 32;
#pragma unroll
    for (int it = 0; it < 3; ++it) {
        int tau = it * 256 + t;
        int sh = tau & 1;
        int g = (tau >> 1) & 3;
        int q = tau >> 3;           // 0..95
        int kkl = q % 3;
        int m_l = q / 3;
        int m = mbase + m_l;
        int kk = kk0 + kkl;
        int b = m >> 10, h = (m >> 5) & 31, wp = m & 31;
        const float2 o = *(const float2*)(offs + (long)m * 72 + (g * 9 + kk) * 2);
        float py = o.x + (float)(h + kk / 3 - 1);
        float px = o.y + (float)(wp + kk % 3 - 1);
        float fy = floorf(py), fx = floorf(px);
        int iy0 = (int)fy, ix0 = (int)fx;
        float wy1 = py - fy, wx1 = px - fx;
        float wy0 = 1.f - wy1, wx0 = 1.f - wx1;
        bool vy0 = iy0 >= 0 && iy0 < 32, vy1 = iy0 + 1 >= 0 && iy0 + 1 < 32;
        bool vx0 = ix0 >= 0 && ix0 < 32, vx1 = ix0 + 1 >= 0 && ix0 + 1 < 32;
        int cy0 = min(max(iy0, 0), 31), cy1 = min(max(iy0 + 1, 0), 31);
        int cx0 = min(max(ix0, 0), 31), cx1 = min(max(ix0 + 1, 0), 31);
        int base = b << 10;
        int c0 = g * 96 + sh * 48;
        const f16* s0 = xh + (long)(base + (cy0 << 5) + cx0) * 384 + c0;
        const f16* s1 = xh + (long)(base + (cy0 << 5) + cx1) * 384 + c0;
        const f16* s2 = xh + (long)(base + (cy1 << 5) + cx0) * 384 + c0;
        const f16* s3 = xh + (long)(base + (cy1 << 5) + cx1) * 384 + c0;
        float w00 = wy0 * wx0 * ((vy0 && vx0) ? 1.f : 0.f);
        float w01 = wy0 * wx1 * ((vy0 && vx1) ? 1.f : 0.f);
        float w10 = wy1 * wx0 * ((vy1 && vx0) ? 1.f : 0.f);
        float w11 = wy1 * wx1 * ((vy1 && vx1) ? 1.f : 0.f);
        f16* dst = As_g + (long)m * 3456 + kk * 384 + c0;
#pragma unroll
        for (int sg = 0; sg < 6; ++sg) {
            f16x8 v0 = *(const f16x8*)(s0 + 8 * sg);
            f16x8 v1 = *(const f16x8*)(s1 + 8 * sg);
            f16x8 v2 = *(const f16x8*)(s2 + 8 * sg);
            f16x8 v3 = *(const f16x8*)(s3 + 8 * sg);
            f16x8 ov;
#pragma unroll
            for (int j = 0; j < 8; ++j)
                ov[j] = (f16)(w00 * (float)v0[j] + w01 * (float)v1[j]
                            + w10 * (float)v2[j] + w11 * (float)v3[j]);
            *(f16x8*)(dst + 8 * sg) = ov;
        }
    }
}

// ---------------- stage B2: dense GEMM M=8192 N=384 K=3456 + BN + SiLU ----------------
// grid (128 m, 4 n), 256 thr (4 waves 2m x 2n). tile 64M x 96N, BK=64.
// global_load_lds staging, XOR-swizzled source + swizzled ds_read (T2 on both A,B).
__global__ __launch_bounds__(256, 2) void k_dcn_gemm2(
        const f16* __restrict__ As_g, const f16* __restrict__ Bp,
        const float* __restrict__ bng, const float* __restrict__ bnb,
        const float* __restrict__ bnm, const float* __restrict__ bnv,
        f16* __restrict__ yh) {
    __shared__ __attribute__((aligned(16))) f16 As[2][64 * 64];
    __shared__ __attribute__((aligned(16))) f16 Bs[2][96 * 64];
    int t = threadIdx.x;
    int bx = blockIdx.x;
    bx = (bx & 7) * 16 + (bx >> 3);        // XCD i <- image i
    int m0 = bx * 64;
    int n0 = blockIdx.y * 96;
    int w = t >> 6, l = t & 63, lr = l & 15, lq = l >> 4;
    int wmi = w & 1, wni = w >> 1;          // wave tile 32M x 48N
    int lrow = l >> 3, col8 = l & 7;
    f32x4 acc[2][3] = {};

    // staging source bases (swizzled col within 128B row)
    // A: 2 instrs, rows f/8 where f = i*256+t ; B: 3 instrs
    const f16* a_src[2];
#pragma unroll
    for (int i = 0; i < 2; ++i) {
        int f = i * 256 + t;
        int ml = f >> 3, c8 = f & 7;
        a_src[i] = As_g + (long)(m0 + ml) * 3456 + ((c8 ^ (ml & 7)) * 8);
    }
    const f16* b_src[3];
#pragma unroll
    for (int i = 0; i < 3; ++i) {
        int f = i * 256 + t;
        int oc = f >> 3, c8 = f & 7;
        b_src[i] = Bp + (long)(n0 + oc) * 64 + ((c8 ^ (oc & 7)) * 8);
    }
    int ldsA = w * 512;                     // halves: wave-uniform base, +lane*16B by HW
    int ldsB = w * 512;

    auto stage = [&](int ck, int buf) {
#pragma unroll
        for (int i = 0; i < 2; ++i)
            GLD_LDS16(a_src[i] + (long)ck * 64, &As[buf][i * 2048 + ldsA]);
#pragma unroll
        for (int i = 0; i < 3; ++i)
            GLD_LDS16(b_src[i] + (long)ck * 24576, &Bs[buf][i * 2048 + ldsB]);
    };
    auto compute = [&](int buf) {
        const char* Ab = (const char*)&As[buf][0];
        const char* Bb = (const char*)&Bs[buf][0];
#pragma unroll
        for (int s = 0; s < 2; ++s) {
            int j = (s << 2) | lq;
            int swz = (j ^ (lr & 7)) * 16;
            f16x8 af[2], bf[3];
#pragma unroll
            for (int mi = 0; mi < 2; ++mi) {
                int row = wmi * 32 + mi * 16 + lr;
                af[mi] = *(const f16x8*)(Ab + row * 128 + swz);
            }
#pragma unroll
            for (int n = 0; n < 3; ++n) {
                int oc = wni * 48 + n * 16 + lr;
                bf[n] = *(const f16x8*)(Bb + oc * 128 + swz);
            }
#pragma unroll
            for (int mi = 0; mi < 2; ++mi)
#pragma unroll
                for (int n = 0; n < 3; ++n)
                    acc[mi][n] = __builtin_amdgcn_mfma_f32_16x16x32_f16(af[mi], bf[n], acc[mi][n], 0, 0, 0);
        }
    };

    stage(0, 0);
    __syncthreads();
    int cur = 0;
    for (int ck = 0; ck < 54; ++ck) {
        if (ck < 53) stage(ck + 1, cur ^ 1);
        compute(cur);
        __syncthreads();
        cur ^= 1;
    }
    // epilogue: BN + SiLU -> yh
#pragma unroll
    for (int n = 0; n < 3; ++n) {
        int oc = n0 + wni * 48 + n * 16 + lr;
        float sc = bng[oc] * rsqrtf(bnv[oc] + EPS_);
        float shf = bnb[oc] - bnm[oc] * sc;
#pragma unroll
        for (int mi = 0; mi < 2; ++mi)
#pragma unroll
            for (int r = 0; r < 4; ++r) {
                int m = m0 + wmi * 32 + mi * 16 + 4 * lq + r;
                float v = acc[mi][n][r] * sc + shf;
                v = v / (1.f + __expf(-v));
                yh[(long)m * 384 + oc] = (f16)v;
            }
    }
}

// ---------------- fallback fused DCN (small ws) — round-3 kernel ----------------
__global__ __launch_bounds__(512, 2) void k_dcn_fused(
        const f16* __restrict__ xh, const float* __restrict__ offs,
        const f16* __restrict__ wp,
        const float* __restrict__ bng, const float* __restrict__ bnb,
        const float* __restrict__ bnm, const float* __restrict__ bnv,
        f16* __restrict__ yh) {
    __shared__ __attribute__((aligned(16))) f16 As[2][64 * 72];
    __shared__ __attribute__((aligned(16))) int ca[2][4][64][4];
    __shared__ __attribute__((aligned(16))) f16x4 cwl[2][4][64];
    int t = threadIdx.x;
    int bx = blockIdx.x;
    bx = (bx & 7) * 16 + (bx >> 3);
    int m0 = bx * 64;
    int n0 = blockIdx.y * 192;
    int w = t >> 6, l = t & 63, lr = l & 15, lq = l >> 4;
    int wm = (w & 1) * 32, wn = (w >> 1) * 48;
    int spx = t >> 3, slot = t & 7;
    const char* xb = (const char*)xh;
    f32x4 acc[2][3] = {};

    auto coords = [&](int kkn, int bufn) {
        if (t < 256) {
            int g = t >> 6, px = t & 63;
            int m = m0 + px;
            int b = m >> 10, h = (m >> 5) & 31, wwp = m & 31;
            int ky = kkn / 3 - 1, kx = kkn % 3 - 1;
            const float2 o = *(const float2*)(offs + (long)m * 72 + (g * 9 + kkn) * 2);
            float py = o.x + (float)(h + ky);
            float pxx = o.y + (float)(wwp + kx);
            float fy = floorf(py), fx = floorf(pxx);
            int iy0 = (int)fy, ix0 = (int)fx;
            float wy1 = py - fy, wx1 = pxx - fx;
            float wy0 = 1.f - wy1, wx0 = 1.f - wx1;
            bool vy0 = iy0 >= 0 && iy0 < 32, vy1 = iy0 + 1 >= 0 && iy0 + 1 < 32;
            bool vx0 = ix0 >= 0 && ix0 < 32, vx1 = ix0 + 1 >= 0 && ix0 + 1 < 32;
            int cy0 = min(max(iy0, 0), 31), cy1 = min(max(iy0 + 1, 0), 31);
            int cx0 = min(max(ix0, 0), 31), cx1 = min(max(ix0 + 1, 0), 31);
            int base = b << 10;
            ca[bufn][g][px][0] = (base + (cy0 << 5) + cx0) * 768;
            ca[bufn][g][px][1] = (base + (cy0 << 5) + cx1) * 768;
            ca[bufn][g][px][2] = (base + (cy1 << 5) + cx0) * 768;
            ca[bufn][g][px][3] = (base + (cy1 << 5) + cx1) * 768;
            f16x4 wv;
            wv.x = (f16)(wy0 * wx0 * ((vy0 && vx0) ? 1.f : 0.f));
            wv.y = (f16)(wy0 * wx1 * ((vy0 && vx1) ? 1.f : 0.f));
            wv.z = (f16)(wy1 * wx0 * ((vy1 && vx0) ? 1.f : 0.f));
            wv.w = (f16)(wy1 * wx1 * ((vy1 && vx1) ? 1.f : 0.f));
            cwl[bufn][g][px] = wv;
        }
    };

    coords(0, 0);
    __syncthreads();
    {
        int cst = 8 * slot;
        int g = cst / 96;
        int4 cv = *(const int4*)(&ca[0][g][spx][0]);
        f16x4 wv = cwl[0][g][spx];
        long cb = (long)(cst * 2);
        f16x8 v0 = *(const f16x8*)(xb + cv.x + cb);
        f16x8 v1 = *(const f16x8*)(xb + cv.y + cb);
        f16x8 v2 = *(const f16x8*)(xb + cv.z + cb);
        f16x8 v3 = *(const f16x8*)(xb + cv.w + cb);
        f16x8 sv = v0 * sp8(wv.x) + v1 * sp8(wv.y) + v2 * sp8(wv.z) + v3 * sp8(wv.w);
        *(f16x8*)(&As[0][spx * 72 + 8 * slot]) = sv;
    }
    int cur = 0, kk = 0, cc = 0;
    for (int ck = 0; ck < 54; ++ck) {
        __syncthreads();
        bool hn = ck < 53;
        int kk2 = kk + (cc == 5), cc2 = (cc == 5) ? 0 : (cc + 1);
        f16x8 v0, v1, v2, v3; f16x4 wv;
        if (hn) {
            int cst = cc2 * 64 + 8 * slot;
            int g = cst / 96;
            int kb = kk2 & 1;
            int4 cv = *(const int4*)(&ca[kb][g][spx][0]);
            wv = cwl[kb][g][spx];
            long cb = (long)(cst * 2);
            v0 = *(const f16x8*)(xb + cv.x + cb);
            v1 = *(const f16x8*)(xb + cv.y + cb);
            v2 = *(const f16x8*)(xb + cv.z + cb);
            v3 = *(const f16x8*)(xb + cv.w + cb);
        }
        if (cc == 4 && kk < 8) coords(kk + 1, (kk + 1) & 1);
        const f16* wbase = wp + (long)ck * (384 * 64);
#pragma unroll
        for (int s = 0; s < 2; ++s) {
            f16x8 a0 = *(const f16x8*)(&As[cur][(wm + lr) * 72 + 32 * s + 8 * lq]);
            f16x8 a1 = *(const f16x8*)(&As[cur][(wm + 16 + lr) * 72 + 32 * s + 8 * lq]);
#pragma unroll
            for (int n = 0; n < 3; ++n) {
                f16x8 b = *(const f16x8*)(wbase + (long)(n0 + wn + 16 * n + lr) * 64 + 32 * s + 8 * lq);
                acc[0][n] = __builtin_amdgcn_mfma_f32_16x16x32_f16(a0, b, acc[0][n], 0, 0, 0);
                acc[1][n] = __builtin_amdgcn_mfma_f32_16x16x32_f16(a1, b, acc[1][n], 0, 0, 0);
            }
        }
        if (hn) {
            f16x8 sv = v0 * sp8(wv.x) + v1 * sp8(wv.y) + v2 * sp8(wv.z) + v3 * sp8(wv.w);
            *(f16x8*)(&As[cur ^ 1][spx * 72 + 8 * slot]) = sv;
        }
        cur ^= 1; kk = kk2; cc = cc2;
    }
#pragma unroll
    for (int n = 0; n < 3; ++n) {
        int oc = n0 + wn + 16 * n + lr;
        float sc = bng[oc] * rsqrtf(bnv[oc] + EPS_);
        float sh = bnb[oc] - bnm[oc] * sc;
#pragma unroll
        for (int mi = 0; mi < 2; ++mi)
#pragma unroll
            for (int r = 0; r < 4; ++r) {
                int m = m0 + wm + 16 * mi + 4 * lq + r;
                float v = acc[mi][n][r] * sc + sh;
                v = v / (1.f + __expf(-v));
                yh[(long)m * 384 + oc] = (f16)v;
            }
    }
}

// ---------------- stage C: 1x1 projection, M=8192 N=384 K=384 ----------------
__global__ __launch_bounds__(256, 4) void k_out_gemm(
        const f16* __restrict__ yh, const f16* __restrict__ wp,
        const float* __restrict__ b2, float* __restrict__ out) {
    __shared__ __attribute__((aligned(16))) f16 As[2][32 * 72];
    int t = threadIdx.x;
    int bx = blockIdx.x;
    bx = (bx & 7) * 32 + (bx >> 3);
    int m0 = bx * 32, n0 = blockIdx.y * 128;
    int w = t >> 6, l = t & 63, lr = l & 15, lq = l >> 4;
    int wn = w * 32;
    int px = t >> 3, slot = t & 7;
    f32x4 acc[2][2] = {};
    const f16* arow = yh + (long)(m0 + px) * 384 + 8 * slot;
    f16x8 stg = *(const f16x8*)(arow);
    *(f16x8*)(&As[0][px * 72 + 8 * slot]) = stg;
    int cur = 0;
    for (int cc = 0; cc < 6; ++cc) {
        __syncthreads();
        bool hn = cc < 5;
        if (hn) stg = *(const f16x8*)(arow + (cc + 1) * 64);
        const f16* wbase = wp + (long)cc * (384 * 64);
#pragma unroll
        for (int s = 0; s < 2; ++s) {
            f16x8 a0 = *(const f16x8*)(&As[cur][(lr) * 72 + 32 * s + 8 * lq]);
            f16x8 a1 = *(const f16x8*)(&As[cur][(16 + lr) * 72 + 32 * s + 8 * lq]);
#pragma unroll
            for (int n = 0; n < 2; ++n) {
                f16x8 b = *(const f16x8*)(wbase + (long)(n0 + wn + 16 * n + lr) * 64 + 32 * s + 8 * lq);
                acc[0][n] = __builtin_amdgcn_mfma_f32_16x16x32_f16(a0, b, acc[0][n], 0, 0, 0);
                acc[1][n] = __builtin_amdgcn_mfma_f32_16x16x32_f16(a1, b, acc[1][n], 0, 0, 0);
            }
        }
        if (hn) *(f16x8*)(&As[cur ^ 1][px * 72 + 8 * slot]) = stg;
        cur ^= 1;
    }
#pragma unroll
    for (int n = 0; n < 2; ++n) {
        int oc = n0 + wn + 16 * n + lr;
        float bia = b2[oc];
#pragma unroll
        for (int mi = 0; mi < 2; ++mi)
#pragma unroll
            for (int r = 0; r < 4; ++r) {
                int m = m0 + 16 * mi + 4 * lq + r;
                out[(long)m * 384 + oc] = acc[mi][n][r] + bia;
            }
    }
}

extern "C" void kernel_launch(void* const* d_in, const int* in_sizes, int n_in,
                              void* d_out, int out_size, void* d_ws, size_t ws_size,
                              hipStream_t stream) {
    const float* x        = (const float*)d_in[0];
    const float* w_off    = (const float*)d_in[1];
    const float* b_off    = (const float*)d_in[2];
    const float* w_dcn    = (const float*)d_in[3];
    const float* bn_gamma = (const float*)d_in[4];
    const float* bn_beta  = (const float*)d_in[5];
    const float* bn_mean  = (const float*)d_in[6];
    const float* bn_var   = (const float*)d_in[7];
    const float* w2       = (const float*)d_in[8];
    const float* b2       = (const float*)d_in[9];

    char* ws = (char*)d_ws;
    f16*   xh    = (f16*)ws;                                  ws += (size_t)N_XH * 2;
    f16*   wdcnp = (f16*)ws;                                  ws += (size_t)N_WDCN * 2;
    f16*   woffp = (f16*)ws;                                  ws += (size_t)N_WOFF * 2;
    f16*   w2p   = (f16*)ws;                                  ws += (size_t)N_W2 * 2;
    float* offs  = (float*)ws;                                ws += (size_t)N_OFFS * 4;
    f16*   yh    = (f16*)ws;                                  ws += (size_t)N_XH * 2;
    f16*   As_g  = (f16*)ws;                                  // big-ws path only

    k_pack<<<13200, 256, 0, stream>>>(x, w_off, w_dcn, w2, xh, woffp, wdcnp, w2p);
    k_off_gemm<<<256, 256, 0, stream>>>(xh, woffp, b_off, offs);

    if (ws_size >= WS_NEED) {
        k_sample<<<768, 256, 0, stream>>>(xh, offs, As_g);
        k_dcn_gemm2<<<dim3(128, 4), 256, 0, stream>>>(As_g, wdcnp,
                bn_gamma, bn_beta, bn_mean, bn_var, yh);
    } else {
        k_dcn_fused<<<dim3(128, 2), 512, 0, stream>>>(xh, offs, wdcnp,
                bn_gamma, bn_beta, bn_mean, bn_var, yh);
    }
    k_out_gemm<<<dim3(256, 3), 256, 0, stream>>>(yh, w2p, b2, (float*)d_out);
}

// Round 5
// 140.655 us; speedup vs baseline: 5.8696x; 1.0868x over previous
//
#include <hip/hip_runtime.h>
#include <math.h>

typedef _Float16 f16;
typedef _Float16 f16x2 __attribute__((ext_vector_type(2)));
typedef _Float16 f16x4 __attribute__((ext_vector_type(4)));
typedef _Float16 f16x8 __attribute__((ext_vector_type(8)));
typedef float f32x4 __attribute__((ext_vector_type(4)));

#define EPS_ 1e-5f

// ws element counts (halves unless noted)
#define N_XH   3145728   // x_h  [8192][384]
#define N_WDCN 1327104   // wdcn_p [54][384][64]
#define N_WOFF 331776    // woff_p [54][96][64]
#define N_W2   147456    // w2_p [6][384][64]
#define N_OFFS 589824    // offs (f32) [8192][72]
#define N_AS   28311552  // A_s [8192][3456]  (big-ws path only)

#define WS_NEED ((size_t)(N_XH + N_WDCN + N_WOFF + N_W2 + N_AS + N_XH) * 2 + (size_t)N_OFFS * 4)

static __device__ __forceinline__ f16x8 sp8(f16 h) { return (f16x8){h,h,h,h,h,h,h,h}; }

#define GLD_LDS16(g, l) __builtin_amdgcn_global_load_lds( \
    (const __attribute__((address_space(1))) void*)(g),   \
    (__attribute__((address_space(3))) void*)(l), 16, 0, 0)

// ---------------- pack: x->f16, weights -> [ck][oc][kc] f16 ----------------
__global__ void k_pack(const float* __restrict__ x, const float* __restrict__ w_off,
                       const float* __restrict__ w_dcn, const float* __restrict__ w2,
                       f16* __restrict__ xh, f16* __restrict__ woffp,
                       f16* __restrict__ wdcnp, f16* __restrict__ w2p) {
    long i = (long)blockIdx.x * 256 + threadIdx.x;
    if (i < 1572864) {                      // x as float2 -> f16x2
        float2 v = ((const float2*)x)[i];
        f16x2 h; h.x = (f16)v.x; h.y = (f16)v.y;
        ((f16x2*)xh)[i] = h;
    } else if (i < 1572864 + 1327104) {     // w_dcn pack [ck=kk*6+cc][384][64]
        long j = i - 1572864;
        int kc = (int)(j & 63); long r = j >> 6;
        int oc = (int)(r % 384); int ck = (int)(r / 384);
        int kk = ck / 6; int c = (ck % 6) * 64 + kc;
        wdcnp[j] = (f16)w_dcn[((long)oc * 384 + c) * 9 + kk];
    } else if (i < 1572864 + 1327104 + 331776) {  // w_off pack [ck][96][64], oc>=72 -> 0
        long j = i - (1572864 + 1327104);
        int kc = (int)(j & 63); long r = j >> 6;
        int oc = (int)(r % 96); int ck = (int)(r / 96);
        int kk = ck / 6; int c = (ck % 6) * 64 + kc;
        woffp[j] = (oc < 72) ? (f16)w_off[((long)oc * 384 + c) * 9 + kk] : (f16)0.f;
    } else if (i < 1572864 + 1327104 + 331776 + 147456) { // w2 pack [cc][384][64]
        long j = i - (1572864 + 1327104 + 331776);
        int kc = (int)(j & 63); long r = j >> 6;
        int oc = (int)(r % 384); int cc = (int)(r / 384);
        w2p[j] = (f16)w2[(long)oc * 384 + cc * 64 + kc];
    }
}

// ---------------- stage A: offset conv, LDS-free split-K fragment GEMM ----------------
// grid (128 m-tiles of 64, 4 k-splits), 256 thr (4 waves 2m x 2n, wave tile 32M x 48N).
// A,B fragments loaded DIRECTLY from global (L2-resident after XCD swizzle).
// Partials to part[ks][8192][72]; reduced (+bias) by k_off_reduce.
__global__ __launch_bounds__(256, 2) void k_off_gemm3(
        const f16* __restrict__ xh, const f16* __restrict__ wp,
        float* __restrict__ part) {
    int t = threadIdx.x;
    int bx = blockIdx.x;
    int ks = blockIdx.y;
    bx = (bx & 7) * 16 + (bx >> 3);        // XCD j <- image j
    int m0 = bx * 64;
    int w = t >> 6, l = t & 63, lr = l & 15, lq = l >> 4;
    int wmi = w & 1, wni = w >> 1;
    int hA[2], wA[2], bbA[2];
#pragma unroll
    for (int mi = 0; mi < 2; ++mi) {
        int r = m0 + wmi * 32 + mi * 16 + lr;
        bbA[mi] = (r >> 10) << 10;
        hA[mi] = (r >> 5) & 31;
        wA[mi] = r & 31;
    }
    int s_ck = (54 * ks) >> 2, e_ck = (54 * (ks + 1)) >> 2;
    f32x4 acc[2][3] = {};

    auto ldA = [&](int kkc, int ccc, f16x8 af[2][2]) {
        int ky = kkc / 3 - 1, kx = kkc % 3 - 1;
#pragma unroll
        for (int mi = 0; mi < 2; ++mi) {
            int hh = hA[mi] + ky, wv = wA[mi] + kx;
            bool ok = ((unsigned)hh < 32u) && ((unsigned)wv < 32u);
            int hc = ok ? hh : 0, wc = ok ? wv : 0;
            const f16* p = xh + (long)(bbA[mi] + (hc << 5) + wc) * 384 + ccc * 64 + 8 * lq;
#pragma unroll
            for (int s = 0; s < 2; ++s) {
                f16x8 v = *(const f16x8*)(p + 32 * s);
                af[mi][s] = ok ? v : (f16x8){};
            }
        }
    };
    auto ldB = [&](int ckc, f16x8 bf[3][2]) {
        const f16* wb = wp + (long)ckc * (96 * 64) + (long)(wni * 48 + lr) * 64 + 8 * lq;
#pragma unroll
        for (int n = 0; n < 3; ++n)
#pragma unroll
            for (int s = 0; s < 2; ++s)
                bf[n][s] = *(const f16x8*)(wb + n * 16 * 64 + 32 * s);
    };
    auto domfma = [&](f16x8 af[2][2], f16x8 bf[3][2]) {
#pragma unroll
        for (int s = 0; s < 2; ++s)
#pragma unroll
            for (int mi = 0; mi < 2; ++mi)
#pragma unroll
                for (int n = 0; n < 3; ++n)
                    acc[mi][n] = __builtin_amdgcn_mfma_f32_16x16x32_f16(af[mi][s], bf[n][s], acc[mi][n], 0, 0, 0);
    };

    int kkc = s_ck / 6, ccc = s_ck % 6;
    f16x8 a0[2][2], b0[3][2], a1[2][2], b1[3][2];
    ldA(kkc, ccc, a0); ldB(s_ck, b0);
    int ck = s_ck;
    while (true) {
        int kk1 = kkc + (ccc == 5), cc1 = (ccc == 5) ? 0 : ccc + 1;
        bool h1 = ck + 1 < e_ck;
        if (h1) { ldA(kk1, cc1, a1); ldB(ck + 1, b1); }
        domfma(a0, b0);
        if (!h1) break;
        int kk2 = kk1 + (cc1 == 5), cc2 = (cc1 == 5) ? 0 : cc1 + 1;
        bool h2 = ck + 2 < e_ck;
        if (h2) { ldA(kk2, cc2, a0); ldB(ck + 2, b0); }
        domfma(a1, b1);
        if (!h2) break;
        kkc = kk2; ccc = cc2;
        ck += 2;
    }
    float* pb = part + (long)ks * (8192 * 72);
#pragma unroll
    for (int n = 0; n < 3; ++n) {
        int oc = wni * 48 + 16 * n + lr;
        if (oc < 72) {
#pragma unroll
            for (int mi = 0; mi < 2; ++mi)
#pragma unroll
                for (int r = 0; r < 4; ++r) {
                    int m = m0 + wmi * 32 + 16 * mi + 4 * lq + r;
                    pb[(long)m * 72 + oc] = acc[mi][n][r];
                }
        }
    }
}

// reduce 4 K-split partials + bias -> offs
__global__ __launch_bounds__(256) void k_off_reduce(
        const float* __restrict__ part, const float* __restrict__ b_off,
        float* __restrict__ offs) {
    int i = blockIdx.x * 256 + threadIdx.x;   // 589824 total
    int oc = i % 72;
    offs[i] = part[i] + part[589824 + i] + part[2 * 589824 + i] + part[3 * 589824 + i] + b_off[oc];
}

// ---------------- stage B1: sampler — materialize A_s[8192][3456] ----------------
__global__ __launch_bounds__(256) void k_sample(
        const f16* __restrict__ xh, const float* __restrict__ offs,
        f16* __restrict__ As_g) {
    int t = threadIdx.x;
    int bid = blockIdx.x;
    int kk0 = (bid >> 8) * 3;
    int mgRaw = bid & 255;
    int mg = (mgRaw & 7) * 32 + (mgRaw >> 3);   // XCD i <- image i
    int mbase = mg * 32;
#pragma unroll
    for (int it = 0; it < 3; ++it) {
        int tau = it * 256 + t;
        int sh = tau & 1;
        int g = (tau >> 1) & 3;
        int q = tau >> 3;           // 0..95
        int kkl = q % 3;
        int m_l = q / 3;
        int m = mbase + m_l;
        int kk = kk0 + kkl;
        int b = m >> 10, h = (m >> 5) & 31, wp = m & 31;
        const float2 o = *(const float2*)(offs + (long)m * 72 + (g * 9 + kk) * 2);
        float py = o.x + (float)(h + kk / 3 - 1);
        float px = o.y + (float)(wp + kk % 3 - 1);
        float fy = floorf(py), fx = floorf(px);
        int iy0 = (int)fy, ix0 = (int)fx;
        float wy1 = py - fy, wx1 = px - fx;
        float wy0 = 1.f - wy1, wx0 = 1.f - wx1;
        bool vy0 = iy0 >= 0 && iy0 < 32, vy1 = iy0 + 1 >= 0 && iy0 + 1 < 32;
        bool vx0 = ix0 >= 0 && ix0 < 32, vx1 = ix0 + 1 >= 0 && ix0 + 1 < 32;
        int cy0 = min(max(iy0, 0), 31), cy1 = min(max(iy0 + 1, 0), 31);
        int cx0 = min(max(ix0, 0), 31), cx1 = min(max(ix0 + 1, 0), 31);
        int base = b << 10;
        int c0 = g * 96 + sh * 48;
        const f16* s0 = xh + (long)(base + (cy0 << 5) + cx0) * 384 + c0;
        const f16* s1 = xh + (long)(base + (cy0 << 5) + cx1) * 384 + c0;
        const f16* s2 = xh + (long)(base + (cy1 << 5) + cx0) * 384 + c0;
        const f16* s3 = xh + (long)(base + (cy1 << 5) + cx1) * 384 + c0;
        float w00 = wy0 * wx0 * ((vy0 && vx0) ? 1.f : 0.f);
        float w01 = wy0 * wx1 * ((vy0 && vx1) ? 1.f : 0.f);
        float w10 = wy1 * wx0 * ((vy1 && vx0) ? 1.f : 0.f);
        float w11 = wy1 * wx1 * ((vy1 && vx1) ? 1.f : 0.f);
        f16* dst = As_g + (long)m * 3456 + kk * 384 + c0;
#pragma unroll
        for (int sg = 0; sg < 6; ++sg) {
            f16x8 v0 = *(const f16x8*)(s0 + 8 * sg);
            f16x8 v1 = *(const f16x8*)(s1 + 8 * sg);
            f16x8 v2 = *(const f16x8*)(s2 + 8 * sg);
            f16x8 v3 = *(const f16x8*)(s3 + 8 * sg);
            f16x8 ov;
#pragma unroll
            for (int j = 0; j < 8; ++j)
                ov[j] = (f16)(w00 * (float)v0[j] + w01 * (float)v1[j]
                            + w10 * (float)v2[j] + w11 * (float)v3[j]);
            *(f16x8*)(dst + 8 * sg) = ov;
        }
    }
}

// ---------------- stage B2: dense GEMM M=8192 N=384 K=3456 + BN + SiLU ----------------
__global__ __launch_bounds__(256, 2) void k_dcn_gemm2(
        const f16* __restrict__ As_g, const f16* __restrict__ Bp,
        const float* __restrict__ bng, const float* __restrict__ bnb,
        const float* __restrict__ bnm, const float* __restrict__ bnv,
        f16* __restrict__ yh) {
    __shared__ __attribute__((aligned(16))) f16 As[2][64 * 64];
    __shared__ __attribute__((aligned(16))) f16 Bs[2][96 * 64];
    int t = threadIdx.x;
    int bx = blockIdx.x;
    bx = (bx & 7) * 16 + (bx >> 3);        // XCD i <- image i
    int m0 = bx * 64;
    int n0 = blockIdx.y * 96;
    int w = t >> 6, l = t & 63, lr = l & 15, lq = l >> 4;
    int wmi = w & 1, wni = w >> 1;          // wave tile 32M x 48N
    f32x4 acc[2][3] = {};

    const f16* a_src[2];
#pragma unroll
    for (int i = 0; i < 2; ++i) {
        int f = i * 256 + t;
        int ml = f >> 3, c8 = f & 7;
        a_src[i] = As_g + (long)(m0 + ml) * 3456 + ((c8 ^ (ml & 7)) * 8);
    }
    const f16* b_src[3];
#pragma unroll
    for (int i = 0; i < 3; ++i) {
        int f = i * 256 + t;
        int oc = f >> 3, c8 = f & 7;
        b_src[i] = Bp + (long)(n0 + oc) * 64 + ((c8 ^ (oc & 7)) * 8);
    }
    int ldsA = w * 512;
    int ldsB = w * 512;

    auto stage = [&](int ck, int buf) {
#pragma unroll
        for (int i = 0; i < 2; ++i)
            GLD_LDS16(a_src[i] + (long)ck * 64, &As[buf][i * 2048 + ldsA]);
#pragma unroll
        for (int i = 0; i < 3; ++i)
            GLD_LDS16(b_src[i] + (long)ck * 24576, &Bs[buf][i * 2048 + ldsB]);
    };
    auto compute = [&](int buf) {
        const char* Ab = (const char*)&As[buf][0];
        const char* Bb = (const char*)&Bs[buf][0];
#pragma unroll
        for (int s = 0; s < 2; ++s) {
            int j = (s << 2) | lq;
            int swz = (j ^ (lr & 7)) * 16;
            f16x8 af[2], bf[3];
#pragma unroll
            for (int mi = 0; mi < 2; ++mi) {
                int row = wmi * 32 + mi * 16 + lr;
                af[mi] = *(const f16x8*)(Ab + row * 128 + swz);
            }
#pragma unroll
            for (int n = 0; n < 3; ++n) {
                int oc = wni * 48 + n * 16 + lr;
                bf[n] = *(const f16x8*)(Bb + oc * 128 + swz);
            }
#pragma unroll
            for (int mi = 0; mi < 2; ++mi)
#pragma unroll
                for (int n = 0; n < 3; ++n)
                    acc[mi][n] = __builtin_amdgcn_mfma_f32_16x16x32_f16(af[mi], bf[n], acc[mi][n], 0, 0, 0);
        }
    };

    stage(0, 0);
    __syncthreads();
    int cur = 0;
    for (int ck = 0; ck < 54; ++ck) {
        if (ck < 53) stage(ck + 1, cur ^ 1);
        compute(cur);
        __syncthreads();
        cur ^= 1;
    }
#pragma unroll
    for (int n = 0; n < 3; ++n) {
        int oc = n0 + wni * 48 + n * 16 + lr;
        float sc = bng[oc] * rsqrtf(bnv[oc] + EPS_);
        float shf = bnb[oc] - bnm[oc] * sc;
#pragma unroll
        for (int mi = 0; mi < 2; ++mi)
#pragma unroll
            for (int r = 0; r < 4; ++r) {
                int m = m0 + wmi * 32 + mi * 16 + 4 * lq + r;
                float v = acc[mi][n][r] * sc + shf;
                v = v / (1.f + __expf(-v));
                yh[(long)m * 384 + oc] = (f16)v;
            }
    }
}

// ---------------- fallback fused DCN (small ws) ----------------
__global__ __launch_bounds__(512, 2) void k_dcn_fused(
        const f16* __restrict__ xh, const float* __restrict__ offs,
        const f16* __restrict__ wp,
        const float* __restrict__ bng, const float* __restrict__ bnb,
        const float* __restrict__ bnm, const float* __restrict__ bnv,
        f16* __restrict__ yh) {
    __shared__ __attribute__((aligned(16))) f16 As[2][64 * 72];
    __shared__ __attribute__((aligned(16))) int ca[2][4][64][4];
    __shared__ __attribute__((aligned(16))) f16x4 cwl[2][4][64];
    int t = threadIdx.x;
    int bx = blockIdx.x;
    bx = (bx & 7) * 16 + (bx >> 3);
    int m0 = bx * 64;
    int n0 = blockIdx.y * 192;
    int w = t >> 6, l = t & 63, lr = l & 15, lq = l >> 4;
    int wm = (w & 1) * 32, wn = (w >> 1) * 48;
    int spx = t >> 3, slot = t & 7;
    const char* xb = (const char*)xh;
    f32x4 acc[2][3] = {};

    auto coords = [&](int kkn, int bufn) {
        if (t < 256) {
            int g = t >> 6, px = t & 63;
            int m = m0 + px;
            int b = m >> 10, h = (m >> 5) & 31, wwp = m & 31;
            int ky = kkn / 3 - 1, kx = kkn % 3 - 1;
            const float2 o = *(const float2*)(offs + (long)m * 72 + (g * 9 + kkn) * 2);
            float py = o.x + (float)(h + ky);
            float pxx = o.y + (float)(wwp + kx);
            float fy = floorf(py), fx = floorf(pxx);
            int iy0 = (int)fy, ix0 = (int)fx;
            float wy1 = py - fy, wx1 = pxx - fx;
            float wy0 = 1.f - wy1, wx0 = 1.f - wx1;
            bool vy0 = iy0 >= 0 && iy0 < 32, vy1 = iy0 + 1 >= 0 && iy0 + 1 < 32;
            bool vx0 = ix0 >= 0 && ix0 < 32, vx1 = ix0 + 1 >= 0 && ix0 + 1 < 32;
            int cy0 = min(max(iy0, 0), 31), cy1 = min(max(iy0 + 1, 0), 31);
            int cx0 = min(max(ix0, 0), 31), cx1 = min(max(ix0 + 1, 0), 31);
            int base = b << 10;
            ca[bufn][g][px][0] = (base + (cy0 << 5) + cx0) * 768;
            ca[bufn][g][px][1] = (base + (cy0 << 5) + cx1) * 768;
            ca[bufn][g][px][2] = (base + (cy1 << 5) + cx0) * 768;
            ca[bufn][g][px][3] = (base + (cy1 << 5) + cx1) * 768;
            f16x4 wv;
            wv.x = (f16)(wy0 * wx0 * ((vy0 && vx0) ? 1.f : 0.f));
            wv.y = (f16)(wy0 * wx1 * ((vy0 && vx1) ? 1.f : 0.f));
            wv.z = (f16)(wy1 * wx0 * ((vy1 && vx0) ? 1.f : 0.f));
            wv.w = (f16)(wy1 * wx1 * ((vy1 && vx1) ? 1.f : 0.f));
            cwl[bufn][g][px] = wv;
        }
    };

    coords(0, 0);
    __syncthreads();
    {
        int cst = 8 * slot;
        int g = cst / 96;
        int4 cv = *(const int4*)(&ca[0][g][spx][0]);
        f16x4 wv = cwl[0][g][spx];
        long cb = (long)(cst * 2);
        f16x8 v0 = *(const f16x8*)(xb + cv.x + cb);
        f16x8 v1 = *(const f16x8*)(xb + cv.y + cb);
        f16x8 v2 = *(const f16x8*)(xb + cv.z + cb);
        f16x8 v3 = *(const f16x8*)(xb + cv.w + cb);
        f16x8 sv = v0 * sp8(wv.x) + v1 * sp8(wv.y) + v2 * sp8(wv.z) + v3 * sp8(wv.w);
        *(f16x8*)(&As[0][spx * 72 + 8 * slot]) = sv;
    }
    int cur = 0, kk = 0, cc = 0;
    for (int ck = 0; ck < 54; ++ck) {
        __syncthreads();
        bool hn = ck < 53;
        int kk2 = kk + (cc == 5), cc2 = (cc == 5) ? 0 : (cc + 1);
        f16x8 v0, v1, v2, v3; f16x4 wv;
        if (hn) {
            int cst = cc2 * 64 + 8 * slot;
            int g = cst / 96;
            int kb = kk2 & 1;
            int4 cv = *(const int4*)(&ca[kb][g][spx][0]);
            wv = cwl[kb][g][spx];
            long cb = (long)(cst * 2);
            v0 = *(const f16x8*)(xb + cv.x + cb);
            v1 = *(const f16x8*)(xb + cv.y + cb);
            v2 = *(const f16x8*)(xb + cv.z + cb);
            v3 = *(const f16x8*)(xb + cv.w + cb);
        }
        if (cc == 4 && kk < 8) coords(kk + 1, (kk + 1) & 1);
        const f16* wbase = wp + (long)ck * (384 * 64);
#pragma unroll
        for (int s = 0; s < 2; ++s) {
            f16x8 a0 = *(const f16x8*)(&As[cur][(wm + lr) * 72 + 32 * s + 8 * lq]);
            f16x8 a1 = *(const f16x8*)(&As[cur][(wm + 16 + lr) * 72 + 32 * s + 8 * lq]);
#pragma unroll
            for (int n = 0; n < 3; ++n) {
                f16x8 b = *(const f16x8*)(wbase + (long)(n0 + wn + 16 * n + lr) * 64 + 32 * s + 8 * lq);
                acc[0][n] = __builtin_amdgcn_mfma_f32_16x16x32_f16(a0, b, acc[0][n], 0, 0, 0);
                acc[1][n] = __builtin_amdgcn_mfma_f32_16x16x32_f16(a1, b, acc[1][n], 0, 0, 0);
            }
        }
        if (hn) {
            f16x8 sv = v0 * sp8(wv.x) + v1 * sp8(wv.y) + v2 * sp8(wv.z) + v3 * sp8(wv.w);
            *(f16x8*)(&As[cur ^ 1][spx * 72 + 8 * slot]) = sv;
        }
        cur ^= 1; kk = kk2; cc = cc2;
    }
#pragma unroll
    for (int n = 0; n < 3; ++n) {
        int oc = n0 + wn + 16 * n + lr;
        float sc = bng[oc] * rsqrtf(bnv[oc] + EPS_);
        float sh = bnb[oc] - bnm[oc] * sc;
#pragma unroll
        for (int mi = 0; mi < 2; ++mi)
#pragma unroll
            for (int r = 0; r < 4; ++r) {
                int m = m0 + wm + 16 * mi + 4 * lq + r;
                float v = acc[mi][n][r] * sc + sh;
                v = v / (1.f + __expf(-v));
                yh[(long)m * 384 + oc] = (f16)v;
            }
    }
}

// ---------------- stage C: 1x1 projection, LDS-free fragment GEMM ----------------
// grid (128, 4), 256 thr (4 waves 2m x 2n, wave tile 32M x 48N). K=384 fully unrolled.
__global__ __launch_bounds__(256, 2) void k_out_gemm2(
        const f16* __restrict__ yh, const f16* __restrict__ wp,
        const float* __restrict__ b2, float* __restrict__ out) {
    int t = threadIdx.x;
    int bx = blockIdx.x;
    bx = (bx & 7) * 16 + (bx >> 3);        // XCD i <- image i
    int m0 = bx * 64;
    int n0 = blockIdx.y * 96;
    int w = t >> 6, l = t & 63, lr = l & 15, lq = l >> 4;
    int wmi = w & 1, wni = w >> 1;
    const f16* arow[2];
#pragma unroll
    for (int mi = 0; mi < 2; ++mi)
        arow[mi] = yh + (long)(m0 + wmi * 32 + mi * 16 + lr) * 384 + 8 * lq;
    f32x4 acc[2][3] = {};
#pragma unroll
    for (int cc = 0; cc < 6; ++cc) {
        f16x8 af[2][2], bf[3][2];
#pragma unroll
        for (int mi = 0; mi < 2; ++mi)
#pragma unroll
            for (int s = 0; s < 2; ++s)
                af[mi][s] = *(const f16x8*)(arow[mi] + cc * 64 + 32 * s);
        const f16* wb = wp + (long)cc * (384 * 64) + (long)(n0 + wni * 48 + lr) * 64 + 8 * lq;
#pragma unroll
        for (int n = 0; n < 3; ++n)
#pragma unroll
            for (int s = 0; s < 2; ++s)
                bf[n][s] = *(const f16x8*)(wb + n * 16 * 64 + 32 * s);
#pragma unroll
        for (int s = 0; s < 2; ++s)
#pragma unroll
            for (int mi = 0; mi < 2; ++mi)
#pragma unroll
                for (int n = 0; n < 3; ++n)
                    acc[mi][n] = __builtin_amdgcn_mfma_f32_16x16x32_f16(af[mi][s], bf[n][s], acc[mi][n], 0, 0, 0);
    }
#pragma unroll
    for (int n = 0; n < 3; ++n) {
        int oc = n0 + wni * 48 + 16 * n + lr;
        float bia = b2[oc];
#pragma unroll
        for (int mi = 0; mi < 2; ++mi)
#pragma unroll
            for (int r = 0; r < 4; ++r) {
                int m = m0 + wmi * 32 + 16 * mi + 4 * lq + r;
                out[(long)m * 384 + oc] = acc[mi][n][r] + bia;
            }
    }
}

extern "C" void kernel_launch(void* const* d_in, const int* in_sizes, int n_in,
                              void* d_out, int out_size, void* d_ws, size_t ws_size,
                              hipStream_t stream) {
    const float* x        = (const float*)d_in[0];
    const float* w_off    = (const float*)d_in[1];
    const float* b_off    = (const float*)d_in[2];
    const float* w_dcn    = (const float*)d_in[3];
    const float* bn_gamma = (const float*)d_in[4];
    const float* bn_beta  = (const float*)d_in[5];
    const float* bn_mean  = (const float*)d_in[6];
    const float* bn_var   = (const float*)d_in[7];
    const float* w2       = (const float*)d_in[8];
    const float* b2       = (const float*)d_in[9];

    char* ws = (char*)d_ws;
    f16*   xh    = (f16*)ws;                                  ws += (size_t)N_XH * 2;
    f16*   wdcnp = (f16*)ws;                                  ws += (size_t)N_WDCN * 2;
    f16*   woffp = (f16*)ws;                                  ws += (size_t)N_WOFF * 2;
    f16*   w2p   = (f16*)ws;                                  ws += (size_t)N_W2 * 2;
    float* offs  = (float*)ws;                                ws += (size_t)N_OFFS * 4;
    f16*   yh    = (f16*)ws;                                  ws += (size_t)N_XH * 2;
    f16*   As_g  = (f16*)ws;                                  // big-ws path only
    // part[4][8192][72] f32 aliases the As_g region (big path): consumed by
    // k_off_reduce before k_sample writes As_g. Small path: lives after yh.
    bool big = ws_size >= WS_NEED;
    float* part = (float*)(big ? (void*)As_g : (void*)ws);

    k_pack<<<13200, 256, 0, stream>>>(x, w_off, w_dcn, w2, xh, woffp, wdcnp, w2p);
    k_off_gemm3<<<dim3(128, 4), 256, 0, stream>>>(xh, woffp, part);
    k_off_reduce<<<2304, 256, 0, stream>>>(part, b_off, offs);

    if (big) {
        k_sample<<<768, 256, 0, stream>>>(xh, offs, As_g);
        k_dcn_gemm2<<<dim3(128, 4), 256, 0, stream>>>(As_g, wdcnp,
                bn_gamma, bn_beta, bn_mean, bn_var, yh);
    } else {
        k_dcn_fused<<<dim3(128, 2), 512, 0, stream>>>(xh, offs, wdcnp,
                bn_gamma, bn_beta, bn_mean, bn_var, yh);
    }
    k_out_gemm2<<<dim3(128, 4), 256, 0, stream>>>(yh, w2p, b2, (float*)d_out);
}

// Round 6
// 140.277 us; speedup vs baseline: 5.8854x; 1.0027x over previous
//
#include <hip/hip_runtime.h>
#include <math.h>

typedef _Float16 f16;
typedef _Float16 f16x2 __attribute__((ext_vector_type(2)));
typedef _Float16 f16x4 __attribute__((ext_vector_type(4)));
typedef _Float16 f16x8 __attribute__((ext_vector_type(8)));
typedef float f32x4 __attribute__((ext_vector_type(4)));

#define EPS_ 1e-5f

// ws element counts (halves unless noted)
#define N_XH   3145728   // x_h  [8192][384]
#define N_WDCN 1327104   // wdcn_p [54][384][64]
#define N_WOFF 331776    // woff_p [54][96][64]
#define N_W2   147456    // w2_p [6][384][64]
#define N_OFFS 589824    // offs (f32) [8192][72]
#define N_AS   28311552  // A_s [8192][3456]  (big-ws path only)

#define WS_NEED ((size_t)(N_XH + N_WDCN + N_WOFF + N_W2 + N_AS + N_XH) * 2 + (size_t)N_OFFS * 4)

static __device__ __forceinline__ f16x8 sp8(f16 h) { return (f16x8){h,h,h,h,h,h,h,h}; }

#define GLD_LDS16(g, l) __builtin_amdgcn_global_load_lds( \
    (const __attribute__((address_space(1))) void*)(g),   \
    (__attribute__((address_space(3))) void*)(l), 16, 0, 0)

#define VMCNT(N) asm volatile("s_waitcnt vmcnt(" #N ")" ::: "memory")

// ---------------- pack: x->f16, weights -> [ck][oc][kc] f16 ----------------
__global__ void k_pack(const float* __restrict__ x, const float* __restrict__ w_off,
                       const float* __restrict__ w_dcn, const float* __restrict__ w2,
                       f16* __restrict__ xh, f16* __restrict__ woffp,
                       f16* __restrict__ wdcnp, f16* __restrict__ w2p) {
    long i = (long)blockIdx.x * 256 + threadIdx.x;
    if (i < 1572864) {                      // x as float2 -> f16x2
        float2 v = ((const float2*)x)[i];
        f16x2 h; h.x = (f16)v.x; h.y = (f16)v.y;
        ((f16x2*)xh)[i] = h;
    } else if (i < 1572864 + 1327104) {     // w_dcn pack [ck=kk*6+cc][384][64]
        long j = i - 1572864;
        int kc = (int)(j & 63); long r = j >> 6;
        int oc = (int)(r % 384); int ck = (int)(r / 384);
        int kk = ck / 6; int c = (ck % 6) * 64 + kc;
        wdcnp[j] = (f16)w_dcn[((long)oc * 384 + c) * 9 + kk];
    } else if (i < 1572864 + 1327104 + 331776) {  // w_off pack [ck][96][64], oc>=72 -> 0
        long j = i - (1572864 + 1327104);
        int kc = (int)(j & 63); long r = j >> 6;
        int oc = (int)(r % 96); int ck = (int)(r / 96);
        int kk = ck / 6; int c = (ck % 6) * 64 + kc;
        woffp[j] = (oc < 72) ? (f16)w_off[((long)oc * 384 + c) * 9 + kk] : (f16)0.f;
    } else if (i < 1572864 + 1327104 + 331776 + 147456) { // w2 pack [cc][384][64]
        long j = i - (1572864 + 1327104 + 331776);
        int kc = (int)(j & 63); long r = j >> 6;
        int oc = (int)(r % 384); int cc = (int)(r / 384);
        w2p[j] = (f16)w2[(long)oc * 384 + cc * 64 + kc];
    }
}

// ---------------- stage A: offset conv, LDS-free split-K fragment GEMM ----------------
// Partials stored TRANSPOSED part[ks][96][8192] as float4 (coalesced).
__global__ __launch_bounds__(256, 2) void k_off_gemm3(
        const f16* __restrict__ xh, const f16* __restrict__ wp,
        float* __restrict__ part) {
    int t = threadIdx.x;
    int bx = blockIdx.x;
    int ks = blockIdx.y;
    bx = (bx & 7) * 16 + (bx >> 3);        // XCD j <- image j
    int m0 = bx * 64;
    int w = t >> 6, l = t & 63, lr = l & 15, lq = l >> 4;
    int wmi = w & 1, wni = w >> 1;
    int hA[2], wA[2], bbA[2];
#pragma unroll
    for (int mi = 0; mi < 2; ++mi) {
        int r = m0 + wmi * 32 + mi * 16 + lr;
        bbA[mi] = (r >> 10) << 10;
        hA[mi] = (r >> 5) & 31;
        wA[mi] = r & 31;
    }
    int s_ck = (54 * ks) >> 2, e_ck = (54 * (ks + 1)) >> 2;
    f32x4 acc[2][3] = {};

    auto ldA = [&](int kkc, int ccc, f16x8 af[2][2]) {
        int ky = kkc / 3 - 1, kx = kkc % 3 - 1;
#pragma unroll
        for (int mi = 0; mi < 2; ++mi) {
            int hh = hA[mi] + ky, wv = wA[mi] + kx;
            bool ok = ((unsigned)hh < 32u) && ((unsigned)wv < 32u);
            int hc = ok ? hh : 0, wc = ok ? wv : 0;
            const f16* p = xh + (long)(bbA[mi] + (hc << 5) + wc) * 384 + ccc * 64 + 8 * lq;
#pragma unroll
            for (int s = 0; s < 2; ++s) {
                f16x8 v = *(const f16x8*)(p + 32 * s);
                af[mi][s] = ok ? v : (f16x8){};
            }
        }
    };
    auto ldB = [&](int ckc, f16x8 bf[3][2]) {
        const f16* wb = wp + (long)ckc * (96 * 64) + (long)(wni * 48 + lr) * 64 + 8 * lq;
#pragma unroll
        for (int n = 0; n < 3; ++n)
#pragma unroll
            for (int s = 0; s < 2; ++s)
                bf[n][s] = *(const f16x8*)(wb + n * 16 * 64 + 32 * s);
    };
    auto domfma = [&](f16x8 af[2][2], f16x8 bf[3][2]) {
#pragma unroll
        for (int s = 0; s < 2; ++s)
#pragma unroll
            for (int mi = 0; mi < 2; ++mi)
#pragma unroll
                for (int n = 0; n < 3; ++n)
                    acc[mi][n] = __builtin_amdgcn_mfma_f32_16x16x32_f16(af[mi][s], bf[n][s], acc[mi][n], 0, 0, 0);
    };

    int kkc = s_ck / 6, ccc = s_ck % 6;
    f16x8 a0[2][2], b0[3][2], a1[2][2], b1[3][2];
    ldA(kkc, ccc, a0); ldB(s_ck, b0);
    int ck = s_ck;
    while (true) {
        int kk1 = kkc + (ccc == 5), cc1 = (ccc == 5) ? 0 : ccc + 1;
        bool h1 = ck + 1 < e_ck;
        if (h1) { ldA(kk1, cc1, a1); ldB(ck + 1, b1); }
        domfma(a0, b0);
        if (!h1) break;
        int kk2 = kk1 + (cc1 == 5), cc2 = (cc1 == 5) ? 0 : cc1 + 1;
        bool h2 = ck + 2 < e_ck;
        if (h2) { ldA(kk2, cc2, a0); ldB(ck + 2, b0); }
        domfma(a1, b1);
        if (!h2) break;
        kkc = kk2; ccc = cc2;
        ck += 2;
    }
    float* pb = part + (long)ks * (96 * 8192);
#pragma unroll
    for (int n = 0; n < 3; ++n) {
        int oc = wni * 48 + 16 * n + lr;
#pragma unroll
        for (int mi = 0; mi < 2; ++mi) {
            int m = m0 + wmi * 32 + 16 * mi + 4 * lq;
            *(f32x4*)(&pb[(long)oc * 8192 + m]) = acc[mi][n];
        }
    }
}

// reduce 4 K-split partials (transposed layout) + bias -> offs[m][72]
__global__ __launch_bounds__(256) void k_off_reduce(
        const float* __restrict__ part, const float* __restrict__ b_off,
        float* __restrict__ offs) {
    int j = blockIdx.x * 256 + threadIdx.x;   // 72*2048 = 147456
    int oc = j >> 11;
    int mq = (j & 2047) << 2;
    const long S = 96L * 8192;
    f32x4 s0 = *(const f32x4*)(&part[(long)oc * 8192 + mq]);
    f32x4 s1 = *(const f32x4*)(&part[S + (long)oc * 8192 + mq]);
    f32x4 s2 = *(const f32x4*)(&part[2 * S + (long)oc * 8192 + mq]);
    f32x4 s3 = *(const f32x4*)(&part[3 * S + (long)oc * 8192 + mq]);
    f32x4 s = s0 + s1 + s2 + s3;
    float b = b_off[oc];
#pragma unroll
    for (int r = 0; r < 4; ++r)
        offs[(long)(mq + r) * 72 + oc] = s[r] + b;
}

// ---------------- stage B1: sampler — materialize A_s[8192][3456] ----------------
__global__ __launch_bounds__(256) void k_sample(
        const f16* __restrict__ xh, const float* __restrict__ offs,
        f16* __restrict__ As_g) {
    int t = threadIdx.x;
    int bid = blockIdx.x;
    int kk0 = (bid >> 8) * 3;
    int mgRaw = bid & 255;
    int mg = (mgRaw & 7) * 32 + (mgRaw >> 3);   // XCD i <- image i
    int mbase = mg * 32;
#pragma unroll
    for (int it = 0; it < 3; ++it) {
        int tau = it * 256 + t;
        int sh = tau & 1;
        int g = (tau >> 1) & 3;
        int q = tau >> 3;           // 0..95
        int kkl = q % 3;
        int m_l = q / 3;
        int m = mbase + m_l;
        int kk = kk0 + kkl;
        int b = m >> 10, h = (m >> 5) & 31, wp = m & 31;
        const float2 o = *(const float2*)(offs + (long)m * 72 + (g * 9 + kk) * 2);
        float py = o.x + (float)(h + kk / 3 - 1);
        float px = o.y + (float)(wp + kk % 3 - 1);
        float fy = floorf(py), fx = floorf(px);
        int iy0 = (int)fy, ix0 = (int)fx;
        float wy1 = py - fy, wx1 = px - fx;
        float wy0 = 1.f - wy1, wx0 = 1.f - wx1;
        bool vy0 = iy0 >= 0 && iy0 < 32, vy1 = iy0 + 1 >= 0 && iy0 + 1 < 32;
        bool vx0 = ix0 >= 0 && ix0 < 32, vx1 = ix0 + 1 >= 0 && ix0 + 1 < 32;
        int cy0 = min(max(iy0, 0), 31), cy1 = min(max(iy0 + 1, 0), 31);
        int cx0 = min(max(ix0, 0), 31), cx1 = min(max(ix0 + 1, 0), 31);
        int base = b << 10;
        int c0 = g * 96 + sh * 48;
        const f16* s0 = xh + (long)(base + (cy0 << 5) + cx0) * 384 + c0;
        const f16* s1 = xh + (long)(base + (cy0 << 5) + cx1) * 384 + c0;
        const f16* s2 = xh + (long)(base + (cy1 << 5) + cx0) * 384 + c0;
        const f16* s3 = xh + (long)(base + (cy1 << 5) + cx1) * 384 + c0;
        float w00 = wy0 * wx0 * ((vy0 && vx0) ? 1.f : 0.f);
        float w01 = wy0 * wx1 * ((vy0 && vx1) ? 1.f : 0.f);
        float w10 = wy1 * wx0 * ((vy1 && vx0) ? 1.f : 0.f);
        float w11 = wy1 * wx1 * ((vy1 && vx1) ? 1.f : 0.f);
        f16* dst = As_g + (long)m * 3456 + kk * 384 + c0;
#pragma unroll
        for (int sg = 0; sg < 6; ++sg) {
            f16x8 v0 = *(const f16x8*)(s0 + 8 * sg);
            f16x8 v1 = *(const f16x8*)(s1 + 8 * sg);
            f16x8 v2 = *(const f16x8*)(s2 + 8 * sg);
            f16x8 v3 = *(const f16x8*)(s3 + 8 * sg);
            f16x8 ov;
#pragma unroll
            for (int j = 0; j < 8; ++j)
                ov[j] = (f16)(w00 * (float)v0[j] + w01 * (float)v1[j]
                            + w10 * (float)v2[j] + w11 * (float)v3[j]);
            *(f16x8*)(dst + 8 * sg) = ov;
        }
    }
}

// ---------------- stage B2: dense GEMM M=8192 N=384 K=3456 + BN + SiLU ----------------
// 3-deep LDS pipeline, counted vmcnt (never drain), raw s_barrier. T2 swizzle kept.
__global__ __launch_bounds__(256, 2) void k_dcn_gemm2(
        const f16* __restrict__ As_g, const f16* __restrict__ Bp,
        const float* __restrict__ bng, const float* __restrict__ bnb,
        const float* __restrict__ bnm, const float* __restrict__ bnv,
        f16* __restrict__ yh) {
    __shared__ __attribute__((aligned(16))) f16 As[3][64 * 64];
    __shared__ __attribute__((aligned(16))) f16 Bs[3][96 * 64];
    int t = threadIdx.x;
    int bx = blockIdx.x;
    bx = (bx & 7) * 16 + (bx >> 3);        // XCD i <- image i
    int m0 = bx * 64;
    int n0 = blockIdx.y * 96;
    int w = t >> 6, l = t & 63, lr = l & 15, lq = l >> 4;
    int wmi = w & 1, wni = w >> 1;          // wave tile 32M x 48N
    f32x4 acc[2][3] = {};

    const f16* a_src[2];
#pragma unroll
    for (int i = 0; i < 2; ++i) {
        int f = i * 256 + t;
        int ml = f >> 3, c8 = f & 7;
        a_src[i] = As_g + (long)(m0 + ml) * 3456 + ((c8 ^ (ml & 7)) * 8);
    }
    const f16* b_src[3];
#pragma unroll
    for (int i = 0; i < 3; ++i) {
        int f = i * 256 + t;
        int oc = f >> 3, c8 = f & 7;
        b_src[i] = Bp + (long)(n0 + oc) * 64 + ((c8 ^ (oc & 7)) * 8);
    }
    int ldsA = w * 512;
    int ldsB = w * 512;

    auto stage = [&](int ck, int buf) {
#pragma unroll
        for (int i = 0; i < 2; ++i)
            GLD_LDS16(a_src[i] + (long)ck * 64, &As[buf][i * 2048 + ldsA]);
#pragma unroll
        for (int i = 0; i < 3; ++i)
            GLD_LDS16(b_src[i] + (long)ck * 24576, &Bs[buf][i * 2048 + ldsB]);
    };
    auto compute = [&](int buf) {
        const char* Ab = (const char*)&As[buf][0];
        const char* Bb = (const char*)&Bs[buf][0];
#pragma unroll
        for (int s = 0; s < 2; ++s) {
            int j = (s << 2) | lq;
            int swz = (j ^ (lr & 7)) * 16;
            f16x8 af[2], bf[3];
#pragma unroll
            for (int mi = 0; mi < 2; ++mi) {
                int row = wmi * 32 + mi * 16 + lr;
                af[mi] = *(const f16x8*)(Ab + row * 128 + swz);
            }
#pragma unroll
            for (int n = 0; n < 3; ++n) {
                int oc = wni * 48 + n * 16 + lr;
                bf[n] = *(const f16x8*)(Bb + oc * 128 + swz);
            }
#pragma unroll
            for (int mi = 0; mi < 2; ++mi)
#pragma unroll
                for (int n = 0; n < 3; ++n)
                    acc[mi][n] = __builtin_amdgcn_mfma_f32_16x16x32_f16(af[mi], bf[n], acc[mi][n], 0, 0, 0);
        }
    };

    stage(0, 0);
    stage(1, 1);
    for (int ck = 0; ck < 54; ++ck) {
        // issue next-next chunk, then wait so that chunk ck's 5 loads are done;
        // keep up to 10 (chunks ck+1, ck+2) in flight across the barrier.
        if (ck + 2 < 54) {
            stage(ck + 2, (ck + 2) % 3);
            VMCNT(10);
        } else if (ck + 1 < 54) {
            VMCNT(5);
        } else {
            VMCNT(0);
        }
        __builtin_amdgcn_s_barrier();      // chunk ck resident for all waves
        compute(ck % 3);
        __builtin_amdgcn_s_barrier();      // all waves done reading buf ck%3
    }
#pragma unroll
    for (int n = 0; n < 3; ++n) {
        int oc = n0 + wni * 48 + n * 16 + lr;
        float sc = bng[oc] * rsqrtf(bnv[oc] + EPS_);
        float shf = bnb[oc] - bnm[oc] * sc;
#pragma unroll
        for (int mi = 0; mi < 2; ++mi)
#pragma unroll
            for (int r = 0; r < 4; ++r) {
                int m = m0 + wmi * 32 + mi * 16 + 4 * lq + r;
                float v = acc[mi][n][r] * sc + shf;
                v = v / (1.f + __expf(-v));
                yh[(long)m * 384 + oc] = (f16)v;
            }
    }
}

// ---------------- fallback fused DCN (small ws) ----------------
__global__ __launch_bounds__(512, 2) void k_dcn_fused(
        const f16* __restrict__ xh, const float* __restrict__ offs,
        const f16* __restrict__ wp,
        const float* __restrict__ bng, const float* __restrict__ bnb,
        const float* __restrict__ bnm, const float* __restrict__ bnv,
        f16* __restrict__ yh) {
    __shared__ __attribute__((aligned(16))) f16 As[2][64 * 72];
    __shared__ __attribute__((aligned(16))) int ca[2][4][64][4];
    __shared__ __attribute__((aligned(16))) f16x4 cwl[2][4][64];
    int t = threadIdx.x;
    int bx = blockIdx.x;
    bx = (bx & 7) * 16 + (bx >> 3);
    int m0 = bx * 64;
    int n0 = blockIdx.y * 192;
    int w = t >> 6, l = t & 63, lr = l & 15, lq = l >> 4;
    int wm = (w & 1) * 32, wn = (w >> 1) * 48;
    int spx = t >> 3, slot = t & 7;
    const char* xb = (const char*)xh;
    f32x4 acc[2][3] = {};

    auto coords = [&](int kkn, int bufn) {
        if (t < 256) {
            int g = t >> 6, px = t & 63;
            int m = m0 + px;
            int b = m >> 10, h = (m >> 5) & 31, wwp = m & 31;
            int ky = kkn / 3 - 1, kx = kkn % 3 - 1;
            const float2 o = *(const float2*)(offs + (long)m * 72 + (g * 9 + kkn) * 2);
            float py = o.x + (float)(h + ky);
            float pxx = o.y + (float)(wwp + kx);
            float fy = floorf(py), fx = floorf(pxx);
            int iy0 = (int)fy, ix0 = (int)fx;
            float wy1 = py - fy, wx1 = pxx - fx;
            float wy0 = 1.f - wy1, wx0 = 1.f - wx1;
            bool vy0 = iy0 >= 0 && iy0 < 32, vy1 = iy0 + 1 >= 0 && iy0 + 1 < 32;
            bool vx0 = ix0 >= 0 && ix0 < 32, vx1 = ix0 + 1 >= 0 && ix0 + 1 < 32;
            int cy0 = min(max(iy0, 0), 31), cy1 = min(max(iy0 + 1, 0), 31);
            int cx0 = min(max(ix0, 0), 31), cx1 = min(max(ix0 + 1, 0), 31);
            int base = b << 10;
            ca[bufn][g][px][0] = (base + (cy0 << 5) + cx0) * 768;
            ca[bufn][g][px][1] = (base + (cy0 << 5) + cx1) * 768;
            ca[bufn][g][px][2] = (base + (cy1 << 5) + cx0) * 768;
            ca[bufn][g][px][3] = (base + (cy1 << 5) + cx1) * 768;
            f16x4 wv;
            wv.x = (f16)(wy0 * wx0 * ((vy0 && vx0) ? 1.f : 0.f));
            wv.y = (f16)(wy0 * wx1 * ((vy0 && vx1) ? 1.f : 0.f));
            wv.z = (f16)(wy1 * wx0 * ((vy1 && vx0) ? 1.f : 0.f));
            wv.w = (f16)(wy1 * wx1 * ((vy1 && vx1) ? 1.f : 0.f));
            cwl[bufn][g][px] = wv;
        }
    };

    coords(0, 0);
    __syncthreads();
    {
        int cst = 8 * slot;
        int g = cst / 96;
        int4 cv = *(const int4*)(&ca[0][g][spx][0]);
        f16x4 wv = cwl[0][g][spx];
        long cb = (long)(cst * 2);
        f16x8 v0 = *(const f16x8*)(xb + cv.x + cb);
        f16x8 v1 = *(const f16x8*)(xb + cv.y + cb);
        f16x8 v2 = *(const f16x8*)(xb + cv.z + cb);
        f16x8 v3 = *(const f16x8*)(xb + cv.w + cb);
        f16x8 sv = v0 * sp8(wv.x) + v1 * sp8(wv.y) + v2 * sp8(wv.z) + v3 * sp8(wv.w);
        *(f16x8*)(&As[0][spx * 72 + 8 * slot]) = sv;
    }
    int cur = 0, kk = 0, cc = 0;
    for (int ck = 0; ck < 54; ++ck) {
        __syncthreads();
        bool hn = ck < 53;
        int kk2 = kk + (cc == 5), cc2 = (cc == 5) ? 0 : (cc + 1);
        f16x8 v0, v1, v2, v3; f16x4 wv;
        if (hn) {
            int cst = cc2 * 64 + 8 * slot;
            int g = cst / 96;
            int kb = kk2 & 1;
            int4 cv = *(const int4*)(&ca[kb][g][spx][0]);
            wv = cwl[kb][g][spx];
            long cb = (long)(cst * 2);
            v0 = *(const f16x8*)(xb + cv.x + cb);
            v1 = *(const f16x8*)(xb + cv.y + cb);
            v2 = *(const f16x8*)(xb + cv.z + cb);
            v3 = *(const f16x8*)(xb + cv.w + cb);
        }
        if (cc == 4 && kk < 8) coords(kk + 1, (kk + 1) & 1);
        const f16* wbase = wp + (long)ck * (384 * 64);
#pragma unroll
        for (int s = 0; s < 2; ++s) {
            f16x8 a0 = *(const f16x8*)(&As[cur][(wm + lr) * 72 + 32 * s + 8 * lq]);
            f16x8 a1 = *(const f16x8*)(&As[cur][(wm + 16 + lr) * 72 + 32 * s + 8 * lq]);
#pragma unroll
            for (int n = 0; n < 3; ++n) {
                f16x8 b = *(const f16x8*)(wbase + (long)(n0 + wn + 16 * n + lr) * 64 + 32 * s + 8 * lq);
                acc[0][n] = __builtin_amdgcn_mfma_f32_16x16x32_f16(a0, b, acc[0][n], 0, 0, 0);
                acc[1][n] = __builtin_amdgcn_mfma_f32_16x16x32_f16(a1, b, acc[1][n], 0, 0, 0);
            }
        }
        if (hn) {
            f16x8 sv = v0 * sp8(wv.x) + v1 * sp8(wv.y) + v2 * sp8(wv.z) + v3 * sp8(wv.w);
            *(f16x8*)(&As[cur ^ 1][spx * 72 + 8 * slot]) = sv;
        }
        cur ^= 1; kk = kk2; cc = cc2;
    }
#pragma unroll
    for (int n = 0; n < 3; ++n) {
        int oc = n0 + wn + 16 * n + lr;
        float sc = bng[oc] * rsqrtf(bnv[oc] + EPS_);
        float sh = bnb[oc] - bnm[oc] * sc;
#pragma unroll
        for (int mi = 0; mi < 2; ++mi)
#pragma unroll
            for (int r = 0; r < 4; ++r) {
                int m = m0 + wm + 16 * mi + 4 * lq + r;
                float v = acc[mi][n][r] * sc + sh;
                v = v / (1.f + __expf(-v));
                yh[(long)m * 384 + oc] = (f16)v;
            }
    }
}

// ---------------- stage C: 1x1 projection, LDS-free fragment GEMM ----------------
__global__ __launch_bounds__(256, 2) void k_out_gemm2(
        const f16* __restrict__ yh, const f16* __restrict__ wp,
        const float* __restrict__ b2, float* __restrict__ out) {
    int t = threadIdx.x;
    int bx = blockIdx.x;
    bx = (bx & 7) * 16 + (bx >> 3);        // XCD i <- image i
    int m0 = bx * 64;
    int n0 = blockIdx.y * 96;
    int w = t >> 6, l = t & 63, lr = l & 15, lq = l >> 4;
    int wmi = w & 1, wni = w >> 1;
    const f16* arow[2];
#pragma unroll
    for (int mi = 0; mi < 2; ++mi)
        arow[mi] = yh + (long)(m0 + wmi * 32 + mi * 16 + lr) * 384 + 8 * lq;
    f32x4 acc[2][3] = {};
#pragma unroll
    for (int cc = 0; cc < 6; ++cc) {
        f16x8 af[2][2], bf[3][2];
#pragma unroll
        for (int mi = 0; mi < 2; ++mi)
#pragma unroll
            for (int s = 0; s < 2; ++s)
                af[mi][s] = *(const f16x8*)(arow[mi] + cc * 64 + 32 * s);
        const f16* wb = wp + (long)cc * (384 * 64) + (long)(n0 + wni * 48 + lr) * 64 + 8 * lq;
#pragma unroll
        for (int n = 0; n < 3; ++n)
#pragma unroll
            for (int s = 0; s < 2; ++s)
                bf[n][s] = *(const f16x8*)(wb + n * 16 * 64 + 32 * s);
#pragma unroll
        for (int s = 0; s < 2; ++s)
#pragma unroll
            for (int mi = 0; mi < 2; ++mi)
#pragma unroll
                for (int n = 0; n < 3; ++n)
                    acc[mi][n] = __builtin_amdgcn_mfma_f32_16x16x32_f16(af[mi][s], bf[n][s], acc[mi][n], 0, 0, 0);
    }
#pragma unroll
    for (int n = 0; n < 3; ++n) {
        int oc = n0 + wni * 48 + 16 * n + lr;
        float bia = b2[oc];
#pragma unroll
        for (int mi = 0; mi < 2; ++mi)
#pragma unroll
            for (int r = 0; r < 4; ++r) {
                int m = m0 + wmi * 32 + 16 * mi + 4 * lq + r;
                out[(long)m * 384 + oc] = acc[mi][n][r] + bia;
            }
    }
}

extern "C" void kernel_launch(void* const* d_in, const int* in_sizes, int n_in,
                              void* d_out, int out_size, void* d_ws, size_t ws_size,
                              hipStream_t stream) {
    const float* x        = (const float*)d_in[0];
    const float* w_off    = (const float*)d_in[1];
    const float* b_off    = (const float*)d_in[2];
    const float* w_dcn    = (const float*)d_in[3];
    const float* bn_gamma = (const float*)d_in[4];
    const float* bn_beta  = (const float*)d_in[5];
    const float* bn_mean  = (const float*)d_in[6];
    const float* bn_var   = (const float*)d_in[7];
    const float* w2       = (const float*)d_in[8];
    const float* b2       = (const float*)d_in[9];

    char* ws = (char*)d_ws;
    f16*   xh    = (f16*)ws;                                  ws += (size_t)N_XH * 2;
    f16*   wdcnp = (f16*)ws;                                  ws += (size_t)N_WDCN * 2;
    f16*   woffp = (f16*)ws;                                  ws += (size_t)N_WOFF * 2;
    f16*   w2p   = (f16*)ws;                                  ws += (size_t)N_W2 * 2;
    float* offs  = (float*)ws;                                ws += (size_t)N_OFFS * 4;
    f16*   yh    = (f16*)ws;                                  ws += (size_t)N_XH * 2;
    f16*   As_g  = (f16*)ws;                                  // big-ws path only
    // part[4][96][8192] f32 aliases As_g (big path): consumed by k_off_reduce
    // before k_sample writes As_g. Small path: lives after yh.
    bool big = ws_size >= WS_NEED;
    float* part = (float*)(big ? (void*)As_g : (void*)ws);

    k_pack<<<13200, 256, 0, stream>>>(x, w_off, w_dcn, w2, xh, woffp, wdcnp, w2p);
    k_off_gemm3<<<dim3(128, 4), 256, 0, stream>>>(xh, woffp, part);
    k_off_reduce<<<576, 256, 0, stream>>>(part, b_off, offs);

    if (big) {
        k_sample<<<768, 256, 0, stream>>>(xh, offs, As_g);
        k_dcn_gemm2<<<dim3(128, 4), 256, 0, stream>>>(As_g, wdcnp,
                bn_gamma, bn_beta, bn_mean, bn_var, yh);
    } else {
        k_dcn_fused<<<dim3(128, 2), 512, 0, stream>>>(xh, offs, wdcnp,
                bn_gamma, bn_beta, bn_mean, bn_var, yh);
    }
    k_out_gemm2<<<dim3(128, 4), 256, 0, stream>>>(yh, w2p, b2, (float*)d_out);
}